// Round 1
// baseline (1517.612 us; speedup 1.0000x reference)
//
#include <hip/hip_runtime.h>

// MFB fused non-local block, MI355X round 1: fp32 tiled-GEMM baseline.
// Pipeline: conv KVQ -> per batch {S=V^T Q, softmax rows in-place, av=K*P (split-K atomics)}
//           -> avw=wwg*av+BN1 -> out=wout*avw+BN2+residual+relu.
// Workspace: K,V,Q,av,avw [B,IC,N] fp32 (5 x 16.8MB) + S [N,N] fp32 (67MB) = 151MB.

#define N_ 4096
#define C_ 512
#define IC_ 256
#define B_ 4
#define TILE 64

// ---------------------------------------------------------------- conv K/V/Q
__global__ __launch_bounds__(256) void conv_kvq_k(
    const float* __restrict__ xA,
    const float* __restrict__ wk, const float* __restrict__ bk,
    const float* __restrict__ wv, const float* __restrict__ bv,
    const float* __restrict__ wq, const float* __restrict__ bq,
    float* __restrict__ Kb, float* __restrict__ Vb, float* __restrict__ Qb)
{
    const int which = blockIdx.z % 3;
    const int b     = blockIdx.z / 3;
    const float* W;
    const float* bias;
    float* Y;
    if (which == 0)      { W = wk; bias = bk; Y = Kb; }
    else if (which == 1) { W = wv; bias = bv; Y = Vb; }
    else                 { W = wq; bias = bq; Y = Qb; }
    const float* X = xA + (size_t)b * C_ * N_;
    Y += (size_t)b * IC_ * N_;

    const int n0 = blockIdx.x * TILE;
    const int o0 = blockIdx.y * TILE;
    const int tx = threadIdx.x, ty = threadIdx.y;
    const int tid = ty * 16 + tx;

    __shared__ float As[16][68];   // As[k][o], pad->no store conflicts
    __shared__ float Bs[16][68];   // Bs[k][n]

    float acc[4][4];
#pragma unroll
    for (int i = 0; i < 4; ++i) {
        const float bi = bias[o0 + ty * 4 + i];
#pragma unroll
        for (int j = 0; j < 4; ++j) acc[i][j] = bi;
    }

    const int aoo = tid >> 2;          // 0..63
    const int ak4 = (tid & 3) << 2;    // 0,4,8,12
    const int bkk = tid >> 4;          // 0..15
    const int bn4 = (tid & 15) << 2;   // 0..60

    for (int kt = 0; kt < C_; kt += 16) {
        const float4 a4 = *(const float4*)&W[(size_t)(o0 + aoo) * C_ + kt + ak4];
        As[ak4 + 0][aoo] = a4.x;
        As[ak4 + 1][aoo] = a4.y;
        As[ak4 + 2][aoo] = a4.z;
        As[ak4 + 3][aoo] = a4.w;
        *(float4*)&Bs[bkk][bn4] = *(const float4*)&X[(size_t)(kt + bkk) * N_ + n0 + bn4];
        __syncthreads();
#pragma unroll
        for (int kk = 0; kk < 16; ++kk) {
            const float4 a  = *(const float4*)&As[kk][ty * 4];
            const float4 bb = *(const float4*)&Bs[kk][tx * 4];
            const float a_[4] = {a.x, a.y, a.z, a.w};
            const float b_[4] = {bb.x, bb.y, bb.z, bb.w};
#pragma unroll
            for (int i = 0; i < 4; ++i)
#pragma unroll
                for (int j = 0; j < 4; ++j) acc[i][j] += a_[i] * b_[j];
        }
        __syncthreads();
    }

#pragma unroll
    for (int i = 0; i < 4; ++i) {
        const float4 o4 = make_float4(acc[i][0], acc[i][1], acc[i][2], acc[i][3]);
        *(float4*)&Y[(size_t)(o0 + ty * 4 + i) * N_ + n0 + tx * 4] = o4;
    }
}

// ---------------------------------------------------------------- S = V^T Q
__global__ __launch_bounds__(256) void s_gemm_k(
    const float* __restrict__ V, const float* __restrict__ Q, float* __restrict__ S)
{
    const int m0 = blockIdx.x * TILE;  // cols m
    const int n0 = blockIdx.y * TILE;  // rows n
    const int tx = threadIdx.x, ty = threadIdx.y;
    const int tid = ty * 16 + tx;

    __shared__ float As[16][68];   // As[c][n]
    __shared__ float Bs[16][68];   // Bs[c][m]

    float acc[4][4];
#pragma unroll
    for (int i = 0; i < 4; ++i)
#pragma unroll
        for (int j = 0; j < 4; ++j) acc[i][j] = 0.0f;

    const int bkk = tid >> 4;
    const int bn4 = (tid & 15) << 2;

    for (int kt = 0; kt < IC_; kt += 16) {
        *(float4*)&As[bkk][bn4] = *(const float4*)&V[(size_t)(kt + bkk) * N_ + n0 + bn4];
        *(float4*)&Bs[bkk][bn4] = *(const float4*)&Q[(size_t)(kt + bkk) * N_ + m0 + bn4];
        __syncthreads();
#pragma unroll
        for (int kk = 0; kk < 16; ++kk) {
            const float4 a  = *(const float4*)&As[kk][ty * 4];
            const float4 bb = *(const float4*)&Bs[kk][tx * 4];
            const float a_[4] = {a.x, a.y, a.z, a.w};
            const float b_[4] = {bb.x, bb.y, bb.z, bb.w};
#pragma unroll
            for (int i = 0; i < 4; ++i)
#pragma unroll
                for (int j = 0; j < 4; ++j) acc[i][j] += a_[i] * b_[j];
        }
        __syncthreads();
    }

#pragma unroll
    for (int i = 0; i < 4; ++i) {
        const float4 o4 = make_float4(acc[i][0], acc[i][1], acc[i][2], acc[i][3]);
        *(float4*)&S[(size_t)(n0 + ty * 4 + i) * N_ + m0 + tx * 4] = o4;
    }
}

// ------------------------------------------------- row softmax, in place S->P
__global__ __launch_bounds__(256) void softmax_rows_k(float* __restrict__ S)
{
    const int row = blockIdx.x;
    float* Sr = S + (size_t)row * N_;
    const int t = threadIdx.x;            // 0..255
    const int lane = t & 63;
    const int wave = t >> 6;

    float4 v[4];
#pragma unroll
    for (int r = 0; r < 4; ++r) v[r] = ((const float4*)Sr)[r * 256 + t];

    float mx = -1e30f;
#pragma unroll
    for (int r = 0; r < 4; ++r)
        mx = fmaxf(mx, fmaxf(fmaxf(v[r].x, v[r].y), fmaxf(v[r].z, v[r].w)));
#pragma unroll
    for (int off = 32; off > 0; off >>= 1) mx = fmaxf(mx, __shfl_down(mx, off));

    __shared__ float red[4];
    if (lane == 0) red[wave] = mx;
    __syncthreads();
    mx = fmaxf(fmaxf(red[0], red[1]), fmaxf(red[2], red[3]));

    float s = 0.0f;
#pragma unroll
    for (int r = 0; r < 4; ++r) {
        v[r].x = __expf(v[r].x - mx);
        v[r].y = __expf(v[r].y - mx);
        v[r].z = __expf(v[r].z - mx);
        v[r].w = __expf(v[r].w - mx);
        s += v[r].x + v[r].y + v[r].z + v[r].w;
    }
#pragma unroll
    for (int off = 32; off > 0; off >>= 1) s += __shfl_down(s, off);

    __syncthreads();   // everyone done reading red (max) before overwrite
    if (lane == 0) red[wave] = s;
    __syncthreads();
    const float inv = 1.0f / (red[0] + red[1] + red[2] + red[3]);

#pragma unroll
    for (int r = 0; r < 4; ++r) {
        v[r].x *= inv; v[r].y *= inv; v[r].z *= inv; v[r].w *= inv;
        ((float4*)Sr)[r * 256 + t] = v[r];
    }
}

// --------------------------------------------- av = K * P, split-K + atomics
__global__ __launch_bounds__(256) void av_gemm_k(
    const float* __restrict__ Kmat, const float* __restrict__ P, float* __restrict__ av)
{
    const int m0 = blockIdx.x * TILE;
    const int c0 = blockIdx.y * TILE;
    const int kbase = blockIdx.z * (N_ / 8);   // 512-wide k chunk
    const int tx = threadIdx.x, ty = threadIdx.y;
    const int tid = ty * 16 + tx;

    __shared__ float As[16][68];   // As[n][c]
    __shared__ float Bs[16][68];   // Bs[n][m]

    float acc[4][4];
#pragma unroll
    for (int i = 0; i < 4; ++i)
#pragma unroll
        for (int j = 0; j < 4; ++j) acc[i][j] = 0.0f;

    const int aoo = tid >> 2;
    const int ak4 = (tid & 3) << 2;
    const int bkk = tid >> 4;
    const int bn4 = (tid & 15) << 2;

    for (int kt = kbase; kt < kbase + (N_ / 8); kt += 16) {
        const float4 a4 = *(const float4*)&Kmat[(size_t)(c0 + aoo) * N_ + kt + ak4];
        As[ak4 + 0][aoo] = a4.x;
        As[ak4 + 1][aoo] = a4.y;
        As[ak4 + 2][aoo] = a4.z;
        As[ak4 + 3][aoo] = a4.w;
        *(float4*)&Bs[bkk][bn4] = *(const float4*)&P[(size_t)(kt + bkk) * N_ + m0 + bn4];
        __syncthreads();
#pragma unroll
        for (int kk = 0; kk < 16; ++kk) {
            const float4 a  = *(const float4*)&As[kk][ty * 4];
            const float4 bb = *(const float4*)&Bs[kk][tx * 4];
            const float a_[4] = {a.x, a.y, a.z, a.w};
            const float b_[4] = {bb.x, bb.y, bb.z, bb.w};
#pragma unroll
            for (int i = 0; i < 4; ++i)
#pragma unroll
                for (int j = 0; j < 4; ++j) acc[i][j] += a_[i] * b_[j];
        }
        __syncthreads();
    }

#pragma unroll
    for (int i = 0; i < 4; ++i)
#pragma unroll
        for (int j = 0; j < 4; ++j)
            atomicAdd(&av[(size_t)(c0 + ty * 4 + i) * N_ + m0 + tx * 4 + j], acc[i][j]);
}

// --------------------------------------------------- avw = wwg*av, BN1 (eval)
__global__ __launch_bounds__(256) void avw_bn1_k(
    const float* __restrict__ wwg, const float* __restrict__ av,
    const float* __restrict__ g1, const float* __restrict__ b1,
    const float* __restrict__ m1, const float* __restrict__ v1,
    float* __restrict__ avw)
{
    const int b = blockIdx.z;
    const float* Bp = av + (size_t)b * IC_ * N_;
    float* Y = avw + (size_t)b * IC_ * N_;

    const int n0 = blockIdx.x * TILE;
    const int o0 = blockIdx.y * TILE;
    const int tx = threadIdx.x, ty = threadIdx.y;
    const int tid = ty * 16 + tx;

    __shared__ float As[16][68];
    __shared__ float Bs[16][68];

    float acc[4][4];
#pragma unroll
    for (int i = 0; i < 4; ++i)
#pragma unroll
        for (int j = 0; j < 4; ++j) acc[i][j] = 0.0f;

    const int aoo = tid >> 2;
    const int ak4 = (tid & 3) << 2;
    const int bkk = tid >> 4;
    const int bn4 = (tid & 15) << 2;

    for (int kt = 0; kt < IC_; kt += 16) {
        const float4 a4 = *(const float4*)&wwg[(size_t)(o0 + aoo) * IC_ + kt + ak4];
        As[ak4 + 0][aoo] = a4.x;
        As[ak4 + 1][aoo] = a4.y;
        As[ak4 + 2][aoo] = a4.z;
        As[ak4 + 3][aoo] = a4.w;
        *(float4*)&Bs[bkk][bn4] = *(const float4*)&Bp[(size_t)(kt + bkk) * N_ + n0 + bn4];
        __syncthreads();
#pragma unroll
        for (int kk = 0; kk < 16; ++kk) {
            const float4 a  = *(const float4*)&As[kk][ty * 4];
            const float4 bb = *(const float4*)&Bs[kk][tx * 4];
            const float a_[4] = {a.x, a.y, a.z, a.w};
            const float b_[4] = {bb.x, bb.y, bb.z, bb.w};
#pragma unroll
            for (int i = 0; i < 4; ++i)
#pragma unroll
                for (int j = 0; j < 4; ++j) acc[i][j] += a_[i] * b_[j];
        }
        __syncthreads();
    }

#pragma unroll
    for (int i = 0; i < 4; ++i) {
        const int o = o0 + ty * 4 + i;
        const float s1 = g1[o] * rsqrtf(v1[o] + 1e-5f);
        const float sh = b1[o] - m1[o] * s1;
        const float4 o4 = make_float4(acc[i][0] * s1 + sh, acc[i][1] * s1 + sh,
                                      acc[i][2] * s1 + sh, acc[i][3] * s1 + sh);
        *(float4*)&Y[(size_t)o * N_ + n0 + tx * 4] = o4;
    }
}

// ------------------------------- out = wout*avw + bout, BN2, +xA, relu
__global__ __launch_bounds__(256) void out_bn2_k(
    const float* __restrict__ wout, const float* __restrict__ bout,
    const float* __restrict__ avw,
    const float* __restrict__ g2, const float* __restrict__ b2,
    const float* __restrict__ m2, const float* __restrict__ v2,
    const float* __restrict__ xA, float* __restrict__ out)
{
    const int b = blockIdx.z;
    const float* Bp = avw + (size_t)b * IC_ * N_;

    const int n0 = blockIdx.x * TILE;
    const int o0 = blockIdx.y * TILE;
    const int tx = threadIdx.x, ty = threadIdx.y;
    const int tid = ty * 16 + tx;

    __shared__ float As[16][68];
    __shared__ float Bs[16][68];

    float acc[4][4];
#pragma unroll
    for (int i = 0; i < 4; ++i)
#pragma unroll
        for (int j = 0; j < 4; ++j) acc[i][j] = 0.0f;

    const int aoo = tid >> 2;
    const int ak4 = (tid & 3) << 2;
    const int bkk = tid >> 4;
    const int bn4 = (tid & 15) << 2;

    for (int kt = 0; kt < IC_; kt += 16) {
        const float4 a4 = *(const float4*)&wout[(size_t)(o0 + aoo) * IC_ + kt + ak4];
        As[ak4 + 0][aoo] = a4.x;
        As[ak4 + 1][aoo] = a4.y;
        As[ak4 + 2][aoo] = a4.z;
        As[ak4 + 3][aoo] = a4.w;
        *(float4*)&Bs[bkk][bn4] = *(const float4*)&Bp[(size_t)(kt + bkk) * N_ + n0 + bn4];
        __syncthreads();
#pragma unroll
        for (int kk = 0; kk < 16; ++kk) {
            const float4 a  = *(const float4*)&As[kk][ty * 4];
            const float4 bb = *(const float4*)&Bs[kk][tx * 4];
            const float a_[4] = {a.x, a.y, a.z, a.w};
            const float b_[4] = {bb.x, bb.y, bb.z, bb.w};
#pragma unroll
            for (int i = 0; i < 4; ++i)
#pragma unroll
                for (int j = 0; j < 4; ++j) acc[i][j] += a_[i] * b_[j];
        }
        __syncthreads();
    }

#pragma unroll
    for (int i = 0; i < 4; ++i) {
        const int o = o0 + ty * 4 + i;
        const float s2 = g2[o] * rsqrtf(v2[o] + 1e-5f);
        const float sh = b2[o] - m2[o] * s2;
        const float bo = bout[o];
        const size_t base = ((size_t)b * C_ + o) * N_ + n0 + tx * 4;
        const float4 r = *(const float4*)&xA[base];
        float4 o4;
        o4.x = fmaxf((acc[i][0] + bo) * s2 + sh + r.x, 0.0f);
        o4.y = fmaxf((acc[i][1] + bo) * s2 + sh + r.y, 0.0f);
        o4.z = fmaxf((acc[i][2] + bo) * s2 + sh + r.z, 0.0f);
        o4.w = fmaxf((acc[i][3] + bo) * s2 + sh + r.w, 0.0f);
        *(float4*)&out[base] = o4;
    }
}

// ---------------------------------------------------------------- launcher
extern "C" void kernel_launch(void* const* d_in, const int* in_sizes, int n_in,
                              void* d_out, int out_size, void* d_ws, size_t ws_size,
                              hipStream_t stream)
{
    const float* xA    = (const float*)d_in[0];
    const float* wk    = (const float*)d_in[1];
    const float* bk    = (const float*)d_in[2];
    const float* wv    = (const float*)d_in[3];
    const float* bv    = (const float*)d_in[4];
    const float* wq    = (const float*)d_in[5];
    const float* bq    = (const float*)d_in[6];
    const float* wwg   = (const float*)d_in[7];
    const float* bn1_g = (const float*)d_in[8];
    const float* bn1_b = (const float*)d_in[9];
    const float* bn1_m = (const float*)d_in[10];
    const float* bn1_v = (const float*)d_in[11];
    const float* wout  = (const float*)d_in[12];
    const float* bout  = (const float*)d_in[13];
    const float* bn2_g = (const float*)d_in[14];
    const float* bn2_b = (const float*)d_in[15];
    const float* bn2_m = (const float*)d_in[16];
    const float* bn2_v = (const float*)d_in[17];
    float* out = (float*)d_out;

    float* ws = (float*)d_ws;
    const size_t ICN = (size_t)IC_ * N_;        // 1,048,576 elements
    float* Kb  = ws;
    float* Vb  = Kb  + ICN * B_;
    float* Qb  = Vb  + ICN * B_;
    float* av  = Qb  + ICN * B_;
    float* avw = av  + ICN * B_;
    float* S   = avw + ICN * B_;                // N*N fp32 (67 MB), reused per batch

    // av accumulated via split-K atomics -> zero it (ws is poisoned 0xAA each call)
    hipMemsetAsync(av, 0, ICN * B_ * sizeof(float), stream);

    const dim3 blk(16, 16);
    conv_kvq_k<<<dim3(N_ / TILE, IC_ / TILE, 3 * B_), blk, 0, stream>>>(
        xA, wk, bk, wv, bv, wq, bq, Kb, Vb, Qb);

    for (int b = 0; b < B_; ++b) {
        s_gemm_k<<<dim3(N_ / TILE, N_ / TILE), blk, 0, stream>>>(
            Vb + (size_t)b * ICN, Qb + (size_t)b * ICN, S);
        softmax_rows_k<<<dim3(N_), dim3(256), 0, stream>>>(S);
        av_gemm_k<<<dim3(N_ / TILE, IC_ / TILE, 8), blk, 0, stream>>>(
            Kb + (size_t)b * ICN, S, av + (size_t)b * ICN);
    }

    avw_bn1_k<<<dim3(N_ / TILE, IC_ / TILE, B_), blk, 0, stream>>>(
        wwg, av, bn1_g, bn1_b, bn1_m, bn1_v, avw);
    out_bn2_k<<<dim3(N_ / TILE, C_ / TILE, B_), blk, 0, stream>>>(
        wout, bout, avw, bn2_g, bn2_b, bn2_m, bn2_v, xA, out);
}

// Round 2
// 705.979 us; speedup vs baseline: 2.1497x; 2.1497x over previous
//
#include <hip/hip_runtime.h>

// MFB fused non-local block, round 2: bf16 MFMA (m97 structure) for all GEMMs.
// exp(S) stored without max-subtraction (|S| <= ~18, fp32-safe); row-sums fused
// into S-GEMM epilogue; transpose+scale produces Pt bf16 for the av GEMM.

#define N_ 4096
#define C_ 512
#define IC_ 256
#define B_ 4

typedef __bf16 bf16_t;
typedef __bf16 bf16x8 __attribute__((ext_vector_type(8)));
typedef __bf16 bf16x4 __attribute__((ext_vector_type(4)));
typedef float f32x4 __attribute__((ext_vector_type(4)));

#define GLD(g, l) __builtin_amdgcn_global_load_lds(                              \
    (const __attribute__((address_space(1))) void*)(g),                          \
    (__attribute__((address_space(3))) void*)(l), 16, 0, 0)

// ---------------------------------------------------------------------------
// Core: C[128x128] += A[m0.., K] * Bt[n0.., K]^T, bf16 in, fp32 acc.
// A row-major [M x K] (lda), Bt row-major [N x K] (ldb), K multiple of 64.
// 256 threads = 4 waves; wave (wr,wc) owns 64x64; acc[4][4] of f32x4.
// ---------------------------------------------------------------------------
__device__ __forceinline__ void gemm_bt_128x128(
    const bf16_t* __restrict__ A, int lda,
    const bf16_t* __restrict__ Bt, int ldb,
    int K, int kt0, int m0, int n0,
    bf16_t* lsA, bf16_t* lsB, f32x4 acc[4][4])
{
    const int tid  = threadIdx.x;
    const int wave = tid >> 6, lane = tid & 63;
    const int wr = (wave >> 1) * 64, wc = (wave & 1) * 64;
    const int q = lane >> 4, l15 = lane & 15;
    const int srow = lane >> 3;          // 0..7 row within 8-row chunk
    const int scol = (lane & 7) * 8;     // 0..56 bf16 col

    for (int kt = kt0; kt < kt0 + K; kt += 64) {
#pragma unroll
        for (int c = 0; c < 4; ++c) {
            const int ch = wave * 4 + c;                 // 16 chunks of 8 rows
            GLD(A  + (size_t)(m0 + ch * 8 + srow) * lda + kt + scol, lsA + ch * 512);
            GLD(Bt + (size_t)(n0 + ch * 8 + srow) * ldb + kt + scol, lsB + ch * 512);
        }
        __syncthreads();   // drains vmcnt -> LDS visible
#pragma unroll
        for (int ks = 0; ks < 2; ++ks) {
            bf16x8 af[4], bfr[4];
#pragma unroll
            for (int i = 0; i < 4; ++i) {
                af[i]  = *(const bf16x8*)&lsA[(wr + i * 16 + l15) * 64 + ks * 32 + q * 8];
                bfr[i] = *(const bf16x8*)&lsB[(wc + i * 16 + l15) * 64 + ks * 32 + q * 8];
            }
#pragma unroll
            for (int i = 0; i < 4; ++i)
#pragma unroll
                for (int j = 0; j < 4; ++j)
                    acc[i][j] = __builtin_amdgcn_mfma_f32_16x16x32_bf16(
                        af[i], bfr[j], acc[i][j], 0, 0, 0);
        }
        __syncthreads();
    }
}

#define ACC_ZERO(acc)                                                           \
    _Pragma("unroll") for (int i = 0; i < 4; ++i)                               \
    _Pragma("unroll") for (int j = 0; j < 4; ++j)                               \
        acc[i][j] = f32x4{0.f, 0.f, 0.f, 0.f};

// C/D layout (m89/m91 verified): element (i,j,reg) -> row wr+i*16+q*4+reg,
//                                                     col wc+j*16+l15.

// --------------------------------------------------------- cast weights bf16
__global__ __launch_bounds__(256) void castw_k(
    const float* __restrict__ wk, const float* __restrict__ wv,
    const float* __restrict__ wq, const float* __restrict__ wwg,
    const float* __restrict__ wout, bf16_t* __restrict__ Wb)
{
    const int i = blockIdx.x * 256 + threadIdx.x;
    float v;
    if      (i < 131072) v = wk[i];
    else if (i < 262144) v = wv[i - 131072];
    else if (i < 393216) v = wq[i - 262144];
    else if (i < 458752) v = wwg[i - 393216];
    else                 v = wout[i - 458752];
    Wb[i] = (bf16_t)v;
}

// --------------------------------------------- xA [b,c,n] -> xAt [b,n,c] bf16
__global__ __launch_bounds__(256) void txa_k(
    const float* __restrict__ xA, bf16_t* __restrict__ xAt)
{
    __shared__ float t[32][33];
    const int b = blockIdx.z;
    const int n0 = blockIdx.x * 32, c0 = blockIdx.y * 32;
    const int tx = threadIdx.x, ty = threadIdx.y;
    const float* X = xA + (size_t)b * C_ * N_;
    bf16_t* Y = xAt + (size_t)b * N_ * C_;
#pragma unroll
    for (int r = 0; r < 4; ++r)
        t[ty + r * 8][tx] = X[(size_t)(c0 + ty + r * 8) * N_ + n0 + tx];
    __syncthreads();
#pragma unroll
    for (int r = 0; r < 4; ++r)
        Y[(size_t)(n0 + ty + r * 8) * C_ + c0 + tx] = (bf16_t)t[tx][ty + r * 8];
}

// ------------------------------------------ conv KVQ: W[o,c] * xAt[n,c]^T
__global__ __launch_bounds__(256) void conv_mfma_k(
    const bf16_t* __restrict__ Wb,
    const float* __restrict__ bk, const float* __restrict__ bv,
    const float* __restrict__ bq, const bf16_t* __restrict__ xAt,
    bf16_t* __restrict__ Kb, bf16_t* __restrict__ Vt, bf16_t* __restrict__ Qt)
{
    __shared__ bf16_t lsA[128 * 64], lsB[128 * 64];
    const int which = blockIdx.z % 3, b = blockIdx.z / 3;
    const bf16_t* A = Wb + which * 131072;
    const float* bias = (which == 0) ? bk : (which == 1 ? bv : bq);
    const bf16_t* Bt = xAt + (size_t)b * N_ * C_;
    const int n0 = blockIdx.x * 128, m0 = blockIdx.y * 128;

    f32x4 acc[4][4];
    ACC_ZERO(acc);
    gemm_bt_128x128(A, C_, Bt, C_, C_, 0, m0, n0, lsA, lsB, acc);

    const int lane = threadIdx.x & 63, wave = threadIdx.x >> 6;
    const int q = lane >> 4, l15 = lane & 15;
    const int wr = (wave >> 1) * 64, wc = (wave & 1) * 64;

    if (which == 0) {                     // K: [o, n], n contiguous
        bf16_t* Y = Kb + (size_t)b * IC_ * N_;
#pragma unroll
        for (int i = 0; i < 4; ++i)
#pragma unroll
            for (int r = 0; r < 4; ++r) {
                const int o = m0 + wr + i * 16 + q * 4 + r;
                const float bo = bias[o];
#pragma unroll
                for (int j = 0; j < 4; ++j)
                    Y[(size_t)o * N_ + n0 + wc + j * 16 + l15] =
                        (bf16_t)(acc[i][j][r] + bo);
            }
    } else {                              // V/Q: [n, o], o contiguous
        bf16_t* Y = ((which == 1) ? Vt : Qt) + (size_t)b * N_ * IC_;
#pragma unroll
        for (int i = 0; i < 4; ++i) {
            const int ob = m0 + wr + i * 16 + q * 4;
            float bo[4];
#pragma unroll
            for (int r = 0; r < 4; ++r) bo[r] = bias[ob + r];
#pragma unroll
            for (int j = 0; j < 4; ++j) {
                const int n = n0 + wc + j * 16 + l15;
                bf16x4 v4;
#pragma unroll
                for (int r = 0; r < 4; ++r) v4[r] = (bf16_t)(acc[i][j][r] + bo[r]);
                *(bf16x4*)&Y[(size_t)n * IC_ + ob] = v4;
            }
        }
    }
}

// ------------- S-GEMM: expS[n,m] = exp(Vt[n,:]·Qt[m,:]); rowsum[n] += sums
__global__ __launch_bounds__(256) void s_mfma_k(
    const bf16_t* __restrict__ Vt, const bf16_t* __restrict__ Qt,
    float* __restrict__ expS, float* __restrict__ rowsum)
{
    __shared__ bf16_t lsA[128 * 64], lsB[128 * 64];
    const int m0 = blockIdx.x * 128;   // cols m
    const int n0 = blockIdx.y * 128;   // rows n

    f32x4 acc[4][4];
    ACC_ZERO(acc);
    gemm_bt_128x128(Vt, IC_, Qt, IC_, IC_, 0, n0, m0, lsA, lsB, acc);

    const int lane = threadIdx.x & 63, wave = threadIdx.x >> 6;
    const int q = lane >> 4, l15 = lane & 15;
    const int wr = (wave >> 1) * 64, wc = (wave & 1) * 64;

#pragma unroll
    for (int i = 0; i < 4; ++i)
#pragma unroll
        for (int r = 0; r < 4; ++r) {
            const int n = n0 + wr + i * 16 + q * 4 + r;
            float rs = 0.f;
#pragma unroll
            for (int j = 0; j < 4; ++j) {
                const float e = __expf(acc[i][j][r]);
                rs += e;
                expS[(size_t)n * N_ + m0 + wc + j * 16 + l15] = e;
            }
            rs += __shfl_xor(rs, 1); rs += __shfl_xor(rs, 2);
            rs += __shfl_xor(rs, 4); rs += __shfl_xor(rs, 8);
            if (l15 == 0) atomicAdd(&rowsum[n], rs);
        }
}

// ----------------- Pt[m,n] = expS[n,m] / rowsum[n]  (transpose + scale, bf16)
__global__ __launch_bounds__(256) void pexp_t_k(
    const float* __restrict__ expS, const float* __restrict__ rowsum,
    bf16_t* __restrict__ Pt)
{
    __shared__ float t[32][33];
    const int n0 = blockIdx.x * 32, m0 = blockIdx.y * 32;
    const int tx = threadIdx.x, ty = threadIdx.y;
#pragma unroll
    for (int r = 0; r < 4; ++r)
        t[ty + r * 8][tx] = expS[(size_t)(n0 + ty + r * 8) * N_ + m0 + tx];
    const float inv = 1.0f / rowsum[n0 + tx];
    __syncthreads();
#pragma unroll
    for (int r = 0; r < 4; ++r)
        Pt[(size_t)(m0 + ty + r * 8) * N_ + n0 + tx] =
            (bf16_t)(t[tx][ty + r * 8] * inv);
}

// -------- av-GEMM: avT[m,c] += K[c,:1024-chunk] · Pt[m,:chunk]  (split-K=4)
__global__ __launch_bounds__(256) void av_mfma_k(
    const bf16_t* __restrict__ Kb, const bf16_t* __restrict__ Pt,
    float* __restrict__ avT)
{
    __shared__ bf16_t lsA[128 * 64], lsB[128 * 64];
    const int m0 = blockIdx.x * 128;        // cols m
    const int c0 = blockIdx.y * 128;        // rows c
    const int kt0 = blockIdx.z * 1024;

    f32x4 acc[4][4];
    ACC_ZERO(acc);
    gemm_bt_128x128(Kb, N_, Pt, N_, 1024, kt0, c0, m0, lsA, lsB, acc);

    const int lane = threadIdx.x & 63, wave = threadIdx.x >> 6;
    const int q = lane >> 4, l15 = lane & 15;
    const int wr = (wave >> 1) * 64, wc = (wave & 1) * 64;

#pragma unroll
    for (int i = 0; i < 4; ++i)
#pragma unroll
        for (int j = 0; j < 4; ++j) {
            const int m = m0 + wc + j * 16 + l15;
            const int c = c0 + wr + i * 16 + q * 4;
#pragma unroll
            for (int r = 0; r < 4; ++r)
                atomicAdd(&avT[(size_t)m * IC_ + c + r], acc[i][j][r]);
        }
}

// ----------------------------------------------------- avT fp32 -> bf16
__global__ __launch_bounds__(256) void cast_av_k(
    const float* __restrict__ avTf, bf16_t* __restrict__ avTb)
{
    const size_t i = (size_t)blockIdx.x * 256 + threadIdx.x;
    avTb[i] = (bf16_t)avTf[i];
}

// --------------- avw-GEMM: avwT[n,o] = BN1(wwg[o,:] · avT[n,:])  bf16 out
__global__ __launch_bounds__(256) void avw_mfma_k(
    const bf16_t* __restrict__ Wwg, const bf16_t* __restrict__ avTb,
    const float* __restrict__ g1, const float* __restrict__ b1,
    const float* __restrict__ m1, const float* __restrict__ v1,
    bf16_t* __restrict__ avwT)
{
    __shared__ bf16_t lsA[128 * 64], lsB[128 * 64];
    const int b = blockIdx.z;
    const bf16_t* Bt = avTb + (size_t)b * N_ * IC_;
    const int n0 = blockIdx.x * 128, o0 = blockIdx.y * 128;

    f32x4 acc[4][4];
    ACC_ZERO(acc);
    gemm_bt_128x128(Wwg, IC_, Bt, IC_, IC_, 0, o0, n0, lsA, lsB, acc);

    const int lane = threadIdx.x & 63, wave = threadIdx.x >> 6;
    const int q = lane >> 4, l15 = lane & 15;
    const int wr = (wave >> 1) * 64, wc = (wave & 1) * 64;
    bf16_t* Y = avwT + (size_t)b * N_ * IC_;

#pragma unroll
    for (int i = 0; i < 4; ++i) {
        const int ob = o0 + wr + i * 16 + q * 4;
        float s1[4], sh[4];
#pragma unroll
        for (int r = 0; r < 4; ++r) {
            s1[r] = g1[ob + r] * rsqrtf(v1[ob + r] + 1e-5f);
            sh[r] = b1[ob + r] - m1[ob + r] * s1[r];
        }
#pragma unroll
        for (int j = 0; j < 4; ++j) {
            const int n = n0 + wc + j * 16 + l15;
            bf16x4 v4;
#pragma unroll
            for (int r = 0; r < 4; ++r)
                v4[r] = (bf16_t)(acc[i][j][r] * s1[r] + sh[r]);
            *(bf16x4*)&Y[(size_t)n * IC_ + ob] = v4;
        }
    }
}

// ---- out-GEMM: out = relu(BN2(wout·avwT^T + bout) + xA)  fp32 out
__global__ __launch_bounds__(256) void out_mfma_k(
    const bf16_t* __restrict__ Wout, const float* __restrict__ bout,
    const bf16_t* __restrict__ avwT,
    const float* __restrict__ g2, const float* __restrict__ b2,
    const float* __restrict__ m2, const float* __restrict__ v2,
    const float* __restrict__ xA, float* __restrict__ out)
{
    __shared__ bf16_t lsA[128 * 64], lsB[128 * 64];
    const int b = blockIdx.z;
    const bf16_t* Bt = avwT + (size_t)b * N_ * IC_;
    const int n0 = blockIdx.x * 128, o0 = blockIdx.y * 128;

    f32x4 acc[4][4];
    ACC_ZERO(acc);
    gemm_bt_128x128(Wout, IC_, Bt, IC_, IC_, 0, o0, n0, lsA, lsB, acc);

    const int lane = threadIdx.x & 63, wave = threadIdx.x >> 6;
    const int q = lane >> 4, l15 = lane & 15;
    const int wr = (wave >> 1) * 64, wc = (wave & 1) * 64;

#pragma unroll
    for (int i = 0; i < 4; ++i) {
        const int ob = o0 + wr + i * 16 + q * 4;
        float s2[4], sh[4], bo[4];
#pragma unroll
        for (int r = 0; r < 4; ++r) {
            s2[r] = g2[ob + r] * rsqrtf(v2[ob + r] + 1e-5f);
            sh[r] = b2[ob + r] - m2[ob + r] * s2[r];
            bo[r] = bout[ob + r];
        }
#pragma unroll
        for (int j = 0; j < 4; ++j) {
            const int n = n0 + wc + j * 16 + l15;
#pragma unroll
            for (int r = 0; r < 4; ++r) {
                const size_t idx = ((size_t)b * C_ + ob + r) * N_ + n;
                const float val = (acc[i][j][r] + bo[r]) * s2[r] + sh[r] + xA[idx];
                out[idx] = fmaxf(val, 0.f);
            }
        }
    }
}

// ---------------------------------------------------------------- launcher
extern "C" void kernel_launch(void* const* d_in, const int* in_sizes, int n_in,
                              void* d_out, int out_size, void* d_ws, size_t ws_size,
                              hipStream_t stream)
{
    const float* xA    = (const float*)d_in[0];
    const float* wk    = (const float*)d_in[1];
    const float* bk    = (const float*)d_in[2];
    const float* wv    = (const float*)d_in[3];
    const float* bv    = (const float*)d_in[4];
    const float* wq    = (const float*)d_in[5];
    const float* bq    = (const float*)d_in[6];
    const float* wwg   = (const float*)d_in[7];
    const float* bn1_g = (const float*)d_in[8];
    const float* bn1_b = (const float*)d_in[9];
    const float* bn1_m = (const float*)d_in[10];
    const float* bn1_v = (const float*)d_in[11];
    const float* wout  = (const float*)d_in[12];
    const float* bout  = (const float*)d_in[13];
    const float* bn2_g = (const float*)d_in[14];
    const float* bn2_b = (const float*)d_in[15];
    const float* bn2_m = (const float*)d_in[16];
    const float* bn2_v = (const float*)d_in[17];
    float* out = (float*)d_out;

    // ---- workspace layout (143.8 MB, aliased) ----
    char* p = (char*)d_ws;
    bf16_t* Wb   = (bf16_t*)p;              p += 1179648;     // wk|wv|wq|wwg|wout bf16
    bf16_t* xAt  = (bf16_t*)p;                                // [b,n,c] bf16 (16.78 MB)
    float*  avTf = (float*)p;               p += 16777216;    // ALIAS: [b,m,c] fp32
    bf16_t* Kb   = (bf16_t*)p;              p += 8388608;     // [b,o,n] bf16
    bf16_t* Vt   = (bf16_t*)p;              p += 8388608;     // [b,n,o] bf16
    bf16_t* Qt   = (bf16_t*)p;              p += 8388608;     // [b,n,o] bf16
    float*  rowsum = (float*)p;             p += 65536;       // [b,n] fp32
    float*  expS = (float*)p;                                 // [n,m] fp32, per-batch (67.1 MB)
    bf16_t* avTb = (bf16_t*)p;                                // ALIAS into expS (8.39 MB)
    bf16_t* avwT = (bf16_t*)(p + 33554432); p += 67108864;    // ALIAS into expS (8.39 MB)
    bf16_t* Pt   = (bf16_t*)p;              p += 33554432;    // [m,n] bf16, per-batch

    const size_t NIC = (size_t)N_ * IC_;

    castw_k<<<2304, 256, 0, stream>>>(wk, wv, wq, wwg, wout, Wb);
    txa_k<<<dim3(N_ / 32, C_ / 32, B_), dim3(32, 8), 0, stream>>>(xA, xAt);
    conv_mfma_k<<<dim3(N_ / 128, IC_ / 128, 3 * B_), 256, 0, stream>>>(
        Wb, bk, bv, bq, xAt, Kb, Vt, Qt);

    // zero split-K accumulator (aliases xAt: safe, conv has consumed xAt) + rowsums
    hipMemsetAsync(avTf, 0, 16777216, stream);
    hipMemsetAsync(rowsum, 0, 65536, stream);

    for (int b = 0; b < B_; ++b) {
        s_mfma_k<<<dim3(N_ / 128, N_ / 128), 256, 0, stream>>>(
            Vt + b * NIC, Qt + b * NIC, expS, rowsum + b * N_);
        pexp_t_k<<<dim3(N_ / 32, N_ / 32), dim3(32, 8), 0, stream>>>(
            expS, rowsum + b * N_, Pt);
        av_mfma_k<<<dim3(N_ / 128, IC_ / 128, 4), 256, 0, stream>>>(
            Kb + b * NIC, Pt, avTf + b * NIC);
    }

    cast_av_k<<<16384, 256, 0, stream>>>(avTf, avTb);
    avw_mfma_k<<<dim3(N_ / 128, IC_ / 128, B_), 256, 0, stream>>>(
        Wb + 393216, avTb, bn1_g, bn1_b, bn1_m, bn1_v, avwT);
    out_mfma_k<<<dim3(N_ / 128, C_ / 128, B_), 256, 0, stream>>>(
        Wb + 458752, bout, avwT, bn2_g, bn2_b, bn2_m, bn2_v, xA, out);
}

// Round 3
// 377.929 us; speedup vs baseline: 4.0156x; 1.8680x over previous
//
#include <hip/hip_runtime.h>

// MFB fused non-local block, round 3.
// - S-GEMM transposed (A=Qt,Bt=Vt) -> epilogue writes Pt[m,n] bf16 (unnormalized
//   exp) via LDS transpose-stage + computes rowsum[n]; no pexp kernel.
// - Normalization folded into K: K' = K / rowsum (kscale, in-place bf16).
// - av GEMM: splitK=8 fp32 partials (no atomics) + reduce/cast kernel.
// - wwg/BN1/wout/BN2 composed into one weight Wf + bias bfv (affine chain),
//   final GEMM: out = relu(Wf . avT + bfv + xA).

#define N_ 4096
#define C_ 512
#define IC_ 256
#define B_ 4

typedef __bf16 bf16_t;
typedef __bf16 bf16x8 __attribute__((ext_vector_type(8)));
typedef __bf16 bf16x4 __attribute__((ext_vector_type(4)));
typedef float f32x4 __attribute__((ext_vector_type(4)));

#define GLD(g, l) __builtin_amdgcn_global_load_lds(                              \
    (const __attribute__((address_space(1))) void*)(g),                          \
    (__attribute__((address_space(3))) void*)(l), 16, 0, 0)

// ---------------------------------------------------------------------------
// C[128x128] += A[m0.., K] * Bt[n0.., K]^T, bf16 in, fp32 acc. K mult of 64.
// 256 threads = 4 waves; wave (wr,wc) owns 64x64; acc[4][4] of f32x4.
// C/D layout (m89/m91): (i,j,reg) -> row wr+i*16+q*4+reg, col wc+j*16+l15.
// ---------------------------------------------------------------------------
__device__ __forceinline__ void gemm_bt_128x128(
    const bf16_t* __restrict__ A, int lda,
    const bf16_t* __restrict__ Bt, int ldb,
    int K, int kt0, int m0, int n0,
    bf16_t* lsA, bf16_t* lsB, f32x4 acc[4][4])
{
    const int tid  = threadIdx.x;
    const int wave = tid >> 6, lane = tid & 63;
    const int wr = (wave >> 1) * 64, wc = (wave & 1) * 64;
    const int q = lane >> 4, l15 = lane & 15;
    const int srow = lane >> 3;          // 0..7
    const int scol = (lane & 7) * 8;     // 0..56

    for (int kt = kt0; kt < kt0 + K; kt += 64) {
#pragma unroll
        for (int c = 0; c < 4; ++c) {
            const int ch = wave * 4 + c;
            GLD(A  + (size_t)(m0 + ch * 8 + srow) * lda + kt + scol, lsA + ch * 512);
            GLD(Bt + (size_t)(n0 + ch * 8 + srow) * ldb + kt + scol, lsB + ch * 512);
        }
        __syncthreads();
#pragma unroll
        for (int ks = 0; ks < 2; ++ks) {
            bf16x8 af[4], bfr[4];
#pragma unroll
            for (int i = 0; i < 4; ++i) {
                af[i]  = *(const bf16x8*)&lsA[(wr + i * 16 + l15) * 64 + ks * 32 + q * 8];
                bfr[i] = *(const bf16x8*)&lsB[(wc + i * 16 + l15) * 64 + ks * 32 + q * 8];
            }
#pragma unroll
            for (int i = 0; i < 4; ++i)
#pragma unroll
                for (int j = 0; j < 4; ++j)
                    acc[i][j] = __builtin_amdgcn_mfma_f32_16x16x32_bf16(
                        af[i], bfr[j], acc[i][j], 0, 0, 0);
        }
        __syncthreads();
    }
}

#define ACC_ZERO(acc)                                                           \
    _Pragma("unroll") for (int i = 0; i < 4; ++i)                               \
    _Pragma("unroll") for (int j = 0; j < 4; ++j)                               \
        acc[i][j] = f32x4{0.f, 0.f, 0.f, 0.f};

// --------------------------------------------------- cast wk|wv|wq to bf16
__global__ __launch_bounds__(256) void castw3_k(
    const float* __restrict__ wk, const float* __restrict__ wv,
    const float* __restrict__ wq, bf16_t* __restrict__ Wb3)
{
    const int i = blockIdx.x * 256 + threadIdx.x;   // 393216 total
    float v;
    if      (i < 131072) v = wk[i];
    else if (i < 262144) v = wv[i - 131072];
    else                 v = wq[i - 262144];
    Wb3[i] = (bf16_t)v;
}

// ---------------- compose Wf = diag(s2) wout diag(s1) wwg,  bfv (all biases)
__global__ __launch_bounds__(256) void wf_k(
    const float* __restrict__ wwg, const float* __restrict__ wout,
    const float* __restrict__ bout,
    const float* __restrict__ g1, const float* __restrict__ b1,
    const float* __restrict__ m1, const float* __restrict__ v1,
    const float* __restrict__ g2, const float* __restrict__ b2,
    const float* __restrict__ m2, const float* __restrict__ v2,
    bf16_t* __restrict__ Wfb, float* __restrict__ bfv)
{
    const int idx = blockIdx.x * 256 + threadIdx.x;
    if (idx >= 512 * 257) return;
    const int o = idx / 257, j = idx % 257;
    const float s2 = g2[o] * rsqrtf(v2[o] + 1e-5f);
    float acc = 0.f;
    if (j < 256) {
        for (int ic = 0; ic < 256; ++ic) {
            const float s1 = g1[ic] * rsqrtf(v1[ic] + 1e-5f);
            acc += wout[o * 256 + ic] * s1 * wwg[ic * 256 + j];
        }
        Wfb[o * 256 + j] = (bf16_t)(acc * s2);
    } else {
        for (int ic = 0; ic < 256; ++ic) {
            const float s1 = g1[ic] * rsqrtf(v1[ic] + 1e-5f);
            acc += wout[o * 256 + ic] * (b1[ic] - m1[ic] * s1);
        }
        bfv[o] = s2 * (acc + bout[o]) - s2 * m2[o] + b2[o];
    }
}

// --------------------------------------------- xA [b,c,n] -> xAt [b,n,c] bf16
__global__ __launch_bounds__(256) void txa_k(
    const float* __restrict__ xA, bf16_t* __restrict__ xAt)
{
    __shared__ float t[32][33];
    const int b = blockIdx.z;
    const int n0 = blockIdx.x * 32, c0 = blockIdx.y * 32;
    const int tx = threadIdx.x, ty = threadIdx.y;
    const float* X = xA + (size_t)b * C_ * N_;
    bf16_t* Y = xAt + (size_t)b * N_ * C_;
#pragma unroll
    for (int r = 0; r < 4; ++r)
        t[ty + r * 8][tx] = X[(size_t)(c0 + ty + r * 8) * N_ + n0 + tx];
    __syncthreads();
#pragma unroll
    for (int r = 0; r < 4; ++r)
        Y[(size_t)(n0 + ty + r * 8) * C_ + c0 + tx] = (bf16_t)t[tx][ty + r * 8];
}

// ------------------------------------------ conv KVQ: W[o,c] * xAt[n,c]^T
__global__ __launch_bounds__(256) void conv_mfma_k(
    const bf16_t* __restrict__ Wb3,
    const float* __restrict__ bk, const float* __restrict__ bv,
    const float* __restrict__ bq, const bf16_t* __restrict__ xAt,
    bf16_t* __restrict__ Kb, bf16_t* __restrict__ Vt, bf16_t* __restrict__ Qt)
{
    __shared__ bf16_t smem[16384];
    const int which = blockIdx.z % 3, b = blockIdx.z / 3;
    const bf16_t* A = Wb3 + which * 131072;
    const float* bias = (which == 0) ? bk : (which == 1 ? bv : bq);
    const bf16_t* Bt = xAt + (size_t)b * N_ * C_;
    const int n0 = blockIdx.x * 128, m0 = blockIdx.y * 128;

    f32x4 acc[4][4];
    ACC_ZERO(acc);
    gemm_bt_128x128(A, C_, Bt, C_, C_, 0, m0, n0, smem, smem + 8192, acc);

    const int lane = threadIdx.x & 63, wave = threadIdx.x >> 6;
    const int q = lane >> 4, l15 = lane & 15;
    const int wr = (wave >> 1) * 64, wc = (wave & 1) * 64;

    if (which == 0) {                     // K: [c, n], n contiguous
        bf16_t* Y = Kb + (size_t)b * IC_ * N_;
#pragma unroll
        for (int i = 0; i < 4; ++i)
#pragma unroll
            for (int r = 0; r < 4; ++r) {
                const int o = m0 + wr + i * 16 + q * 4 + r;
                const float bo = bias[o];
#pragma unroll
                for (int j = 0; j < 4; ++j)
                    Y[(size_t)o * N_ + n0 + wc + j * 16 + l15] =
                        (bf16_t)(acc[i][j][r] + bo);
            }
    } else {                              // V/Q: [n, c], c contiguous
        bf16_t* Y = ((which == 1) ? Vt : Qt) + (size_t)b * N_ * IC_;
#pragma unroll
        for (int i = 0; i < 4; ++i) {
            const int ob = m0 + wr + i * 16 + q * 4;
            float bo[4];
#pragma unroll
            for (int r = 0; r < 4; ++r) bo[r] = bias[ob + r];
#pragma unroll
            for (int j = 0; j < 4; ++j) {
                const int n = n0 + wc + j * 16 + l15;
                bf16x4 v4;
#pragma unroll
                for (int r = 0; r < 4; ++r) v4[r] = (bf16_t)(acc[i][j][r] + bo[r]);
                *(bf16x4*)&Y[(size_t)n * IC_ + ob] = v4;
            }
        }
    }
}

// ---- S^T GEMM: D[m,n] = Qt[m,:].Vt[n,:] = S[n,m]; write Pt[m,n]=exp(D) bf16,
//      rowsum[n] += column sums. LDS stage (stride 136) -> b128 stores.
__global__ __launch_bounds__(256) void s_mfma_t_k(
    const bf16_t* __restrict__ Qt, const bf16_t* __restrict__ Vt,
    bf16_t* __restrict__ Pt, float* __restrict__ rowsum)
{
    __shared__ bf16_t smem[17408];        // 34.8 KB: A/B staging, then C stage
    const int n0 = blockIdx.x * 128;      // cols (n)
    const int m0 = blockIdx.y * 128;      // rows (m)

    f32x4 acc[4][4];
    ACC_ZERO(acc);
    gemm_bt_128x128(Qt, IC_, Vt, IC_, IC_, 0, m0, n0, smem, smem + 8192, acc);

    const int tid = threadIdx.x;
    const int lane = tid & 63, wave = tid >> 6;
    const int q = lane >> 4, l15 = lane & 15;
    const int wr = (wave >> 1) * 64, wc = (wave & 1) * 64;

#pragma unroll
    for (int j = 0; j < 4; ++j) {
        float cs = 0.f;
#pragma unroll
        for (int i = 0; i < 4; ++i)
#pragma unroll
            for (int r = 0; r < 4; ++r) {
                const float e = __expf(acc[i][j][r]);
                cs += e;
                smem[(wr + i * 16 + q * 4 + r) * 136 + wc + j * 16 + l15] = (bf16_t)e;
            }
        cs += __shfl_xor(cs, 16);
        cs += __shfl_xor(cs, 32);
        if (q == 0) atomicAdd(&rowsum[n0 + wc + j * 16 + l15], cs);
    }
    __syncthreads();

    const int rr = tid >> 4;              // 0..15
    const int cc = (tid & 15) * 8;        // 0..120
#pragma unroll
    for (int p = 0; p < 8; ++p) {
        const int mm = rr + p * 16;
        const bf16x8 v = *(const bf16x8*)&smem[mm * 136 + cc];
        *(bf16x8*)&Pt[(size_t)(m0 + mm) * N_ + n0 + cc] = v;
    }
}

// --------------------------- K'[c,n] = K[c,n] / rowsum[n], in-place bf16
__global__ __launch_bounds__(256) void kscale_k(
    bf16_t* __restrict__ Kb, const float* __restrict__ rowsum)
{
    const int t = blockIdx.x * 256 + threadIdx.x;   // 131072 threads
    const int i8 = t * 8;
    const int n = i8 & (N_ - 1);
    bf16x8 v = *(bf16x8*)&Kb[i8];
    const f32x4 r0 = *(const f32x4*)&rowsum[n];
    const f32x4 r1 = *(const f32x4*)&rowsum[n + 4];
#pragma unroll
    for (int k = 0; k < 4; ++k) {
        v[k]     = (bf16_t)((float)v[k]     / r0[k]);
        v[4 + k] = (bf16_t)((float)v[4 + k] / r1[k]);
    }
    *(bf16x8*)&Kb[i8] = v;
}

// ------- av GEMM: avPart[z][m][c] = Pt[m, kchunk] . K'[c, kchunk]^T (splitK=8)
__global__ __launch_bounds__(256) void av_mfma_k(
    const bf16_t* __restrict__ Pt, const bf16_t* __restrict__ Kb,
    float* __restrict__ avPart)
{
    __shared__ bf16_t smem[16384];
    const int m0 = blockIdx.x * 128;      // rows m
    const int c0 = blockIdx.y * 128;      // cols c
    const int z  = blockIdx.z;            // 0..7

    f32x4 acc[4][4];
    ACC_ZERO(acc);
    gemm_bt_128x128(Pt, N_, Kb, N_, 512, z * 512, m0, c0, smem, smem + 8192, acc);

    const int lane = threadIdx.x & 63, wave = threadIdx.x >> 6;
    const int q = lane >> 4, l15 = lane & 15;
    const int wr = (wave >> 1) * 64, wc = (wave & 1) * 64;
    float* Y = avPart + (size_t)z * N_ * IC_;

#pragma unroll
    for (int i = 0; i < 4; ++i)
#pragma unroll
        for (int r = 0; r < 4; ++r) {
            const int m = m0 + wr + i * 16 + q * 4 + r;
#pragma unroll
            for (int j = 0; j < 4; ++j)
                Y[(size_t)m * IC_ + c0 + wc + j * 16 + l15] = acc[i][j][r];
        }
}

// ------------------------- avTb[m][c] = bf16( sum_z avPart[z][m][c] )
__global__ __launch_bounds__(256) void avred_k(
    const float* __restrict__ avPart, bf16_t* __restrict__ avTb)
{
    const size_t i8 = ((size_t)blockIdx.x * 256 + threadIdx.x) * 8;
    f32x4 s0 = {0.f, 0.f, 0.f, 0.f}, s1 = {0.f, 0.f, 0.f, 0.f};
#pragma unroll
    for (int z = 0; z < 8; ++z) {
        s0 += *(const f32x4*)&avPart[(size_t)z * N_ * IC_ + i8];
        s1 += *(const f32x4*)&avPart[(size_t)z * N_ * IC_ + i8 + 4];
    }
    bf16x8 o;
#pragma unroll
    for (int k = 0; k < 4; ++k) { o[k] = (bf16_t)s0[k]; o[4 + k] = (bf16_t)s1[k]; }
    *(bf16x8*)&avTb[i8] = o;
}

// ------------ final: out = relu( Wf . avT + bfv + xA ), fp32 out
__global__ __launch_bounds__(256) void out_mfma_k(
    const bf16_t* __restrict__ Wfb, const float* __restrict__ bfv,
    const bf16_t* __restrict__ avTb,
    const float* __restrict__ xA, float* __restrict__ out)
{
    __shared__ bf16_t smem[16384];
    const int b = blockIdx.z;
    const bf16_t* Bt = avTb + (size_t)b * N_ * IC_;
    const int n0 = blockIdx.x * 128, o0 = blockIdx.y * 128;

    f32x4 acc[4][4];
    ACC_ZERO(acc);
    gemm_bt_128x128(Wfb, IC_, Bt, IC_, IC_, 0, o0, n0, smem, smem + 8192, acc);

    const int lane = threadIdx.x & 63, wave = threadIdx.x >> 6;
    const int q = lane >> 4, l15 = lane & 15;
    const int wr = (wave >> 1) * 64, wc = (wave & 1) * 64;

#pragma unroll
    for (int i = 0; i < 4; ++i)
#pragma unroll
        for (int r = 0; r < 4; ++r) {
            const int o = o0 + wr + i * 16 + q * 4 + r;
            const float bo = bfv[o];
#pragma unroll
            for (int j = 0; j < 4; ++j) {
                const int n = n0 + wc + j * 16 + l15;
                const size_t idx = ((size_t)b * C_ + o) * N_ + n;
                out[idx] = fmaxf(acc[i][j][r] + bo + xA[idx], 0.f);
            }
        }
}

// ---------------------------------------------------------------- launcher
extern "C" void kernel_launch(void* const* d_in, const int* in_sizes, int n_in,
                              void* d_out, int out_size, void* d_ws, size_t ws_size,
                              hipStream_t stream)
{
    const float* xA    = (const float*)d_in[0];
    const float* wk    = (const float*)d_in[1];
    const float* bk    = (const float*)d_in[2];
    const float* wv    = (const float*)d_in[3];
    const float* bv    = (const float*)d_in[4];
    const float* wq    = (const float*)d_in[5];
    const float* bq    = (const float*)d_in[6];
    const float* wwg   = (const float*)d_in[7];
    const float* bn1_g = (const float*)d_in[8];
    const float* bn1_b = (const float*)d_in[9];
    const float* bn1_m = (const float*)d_in[10];
    const float* bn1_v = (const float*)d_in[11];
    const float* wout  = (const float*)d_in[12];
    const float* bout  = (const float*)d_in[13];
    const float* bn2_g = (const float*)d_in[14];
    const float* bn2_b = (const float*)d_in[15];
    const float* bn2_m = (const float*)d_in[16];
    const float* bn2_v = (const float*)d_in[17];
    float* out = (float*)d_out;

    // ---- workspace layout (118.6 MB) ----
    char* p = (char*)d_ws;
    bf16_t* Wb3    = (bf16_t*)p; p += 786432;     // wk|wv|wq bf16
    bf16_t* Wfb    = (bf16_t*)p; p += 262144;     // composed weight [512,256]
    float*  bfv    = (float*)p;  p += 2048;       // composed bias [512]
    bf16_t* xAt    = (bf16_t*)p; p += 16777216;   // [b,n,c]
    bf16_t* Kb     = (bf16_t*)p; p += 8388608;    // [b,c,n]  (scaled in-place)
    bf16_t* Vt     = (bf16_t*)p; p += 8388608;    // [b,n,c]
    bf16_t* Qt     = (bf16_t*)p; p += 8388608;    // [b,n,c]
    float*  rowsum = (float*)p;  p += 65536;      // [b,n]
    bf16_t* Pt     = (bf16_t*)p; p += 33554432;   // [m,n] per-batch
    float*  avPart = (float*)p;  p += 33554432;   // [8][m][c] per-batch
    bf16_t* avTb   = (bf16_t*)p; p += 8388608;    // [b,m,c]

    const size_t NIC = (size_t)N_ * IC_;

    castw3_k<<<1536, 256, 0, stream>>>(wk, wv, wq, Wb3);
    wf_k<<<514, 256, 0, stream>>>(wwg, wout, bout, bn1_g, bn1_b, bn1_m, bn1_v,
                                  bn2_g, bn2_b, bn2_m, bn2_v, Wfb, bfv);
    txa_k<<<dim3(N_ / 32, C_ / 32, B_), dim3(32, 8), 0, stream>>>(xA, xAt);
    conv_mfma_k<<<dim3(N_ / 128, IC_ / 128, 3 * B_), 256, 0, stream>>>(
        Wb3, bk, bv, bq, xAt, Kb, Vt, Qt);

    hipMemsetAsync(rowsum, 0, 65536, stream);

    for (int b = 0; b < B_; ++b) {
        s_mfma_t_k<<<dim3(N_ / 128, N_ / 128), 256, 0, stream>>>(
            Qt + b * NIC, Vt + b * NIC, Pt, rowsum + b * N_);
        kscale_k<<<512, 256, 0, stream>>>(Kb + b * NIC, rowsum + b * N_);
        av_mfma_k<<<dim3(N_ / 128, IC_ / 128, 8), 256, 0, stream>>>(
            Pt, Kb + b * NIC, avPart);
        avred_k<<<512, 256, 0, stream>>>(avPart, avTb + b * NIC);
    }

    out_mfma_k<<<dim3(N_ / 128, C_ / 128, B_), 256, 0, stream>>>(
        Wfb, bfv, avTb, xA, out);
}

// Round 5
// 346.904 us; speedup vs baseline: 4.3747x; 1.0894x over previous
//
#include <hip/hip_runtime.h>

// MFB fused non-local block, round 4b (compile fix of r4).
// - wf_k rewritten: LDS-staged row, coalesced wwg reads, shuffle-reduced bias.
// - All per-batch loops batched via blockIdx.z (ws=256MiB confirmed):
//   Pt all-batch 134MB, avPart splitK=4 67MB, avTb aliases dead xAt. 10 dispatches.

#define N_ 4096
#define C_ 512
#define IC_ 256
#define B_ 4

typedef __bf16 bf16_t;
typedef __bf16 bf16x8 __attribute__((ext_vector_type(8)));
typedef __bf16 bf16x4 __attribute__((ext_vector_type(4)));
typedef float f32x4 __attribute__((ext_vector_type(4)));

#define GLD(g, l) __builtin_amdgcn_global_load_lds(                              \
    (const __attribute__((address_space(1))) void*)(g),                          \
    (__attribute__((address_space(3))) void*)(l), 16, 0, 0)

// ---------------------------------------------------------------------------
// C[128x128] += A[m0.., K] * Bt[n0.., K]^T, bf16 in, fp32 acc. K mult of 64.
// 256 threads = 4 waves; wave (wr,wc) owns 64x64; acc[4][4] of f32x4.
// C/D layout (m89/m91): (i,j,reg) -> row wr+i*16+q*4+reg, col wc+j*16+l15.
// ---------------------------------------------------------------------------
__device__ __forceinline__ void gemm_bt_128x128(
    const bf16_t* __restrict__ A, int lda,
    const bf16_t* __restrict__ Bt, int ldb,
    int K, int kt0, int m0, int n0,
    bf16_t* lsA, bf16_t* lsB, f32x4 acc[4][4])
{
    const int tid  = threadIdx.x;
    const int wave = tid >> 6, lane = tid & 63;
    const int wr = (wave >> 1) * 64, wc = (wave & 1) * 64;
    const int q = lane >> 4, l15 = lane & 15;
    const int srow = lane >> 3;          // 0..7
    const int scol = (lane & 7) * 8;     // 0..56

    for (int kt = kt0; kt < kt0 + K; kt += 64) {
#pragma unroll
        for (int c = 0; c < 4; ++c) {
            const int ch = wave * 4 + c;
            GLD(A  + (size_t)(m0 + ch * 8 + srow) * lda + kt + scol, lsA + ch * 512);
            GLD(Bt + (size_t)(n0 + ch * 8 + srow) * ldb + kt + scol, lsB + ch * 512);
        }
        __syncthreads();
#pragma unroll
        for (int ks = 0; ks < 2; ++ks) {
            bf16x8 af[4], bfr[4];
#pragma unroll
            for (int i = 0; i < 4; ++i) {
                af[i]  = *(const bf16x8*)&lsA[(wr + i * 16 + l15) * 64 + ks * 32 + q * 8];
                bfr[i] = *(const bf16x8*)&lsB[(wc + i * 16 + l15) * 64 + ks * 32 + q * 8];
            }
#pragma unroll
            for (int i = 0; i < 4; ++i)
#pragma unroll
                for (int j = 0; j < 4; ++j)
                    acc[i][j] = __builtin_amdgcn_mfma_f32_16x16x32_bf16(
                        af[i], bfr[j], acc[i][j], 0, 0, 0);
        }
        __syncthreads();
    }
}

#define ACC_ZERO(acc)                                                           \
    _Pragma("unroll") for (int i = 0; i < 4; ++i)                               \
    _Pragma("unroll") for (int j = 0; j < 4; ++j)                               \
        acc[i][j] = f32x4{0.f, 0.f, 0.f, 0.f};

// --------------------------------------------------- cast wk|wv|wq to bf16
__global__ __launch_bounds__(256) void castw3_k(
    const float* __restrict__ wk, const float* __restrict__ wv,
    const float* __restrict__ wq, bf16_t* __restrict__ Wb3)
{
    const int i = blockIdx.x * 256 + threadIdx.x;   // 393216 total
    float v;
    if      (i < 131072) v = wk[i];
    else if (i < 262144) v = wv[i - 131072];
    else                 v = wq[i - 262144];
    Wb3[i] = (bf16_t)v;
}

// ---- compose Wf = diag(s2) wout diag(s1) wwg, bfv (all biases folded).
// One block per row o; thread j sweeps ic with coalesced wwg reads (L2-hit).
__global__ __launch_bounds__(256) void wf_k(
    const float* __restrict__ wwg, const float* __restrict__ wout,
    const float* __restrict__ bout,
    const float* __restrict__ g1, const float* __restrict__ b1,
    const float* __restrict__ m1, const float* __restrict__ v1,
    const float* __restrict__ g2, const float* __restrict__ b2,
    const float* __restrict__ m2, const float* __restrict__ v2,
    bf16_t* __restrict__ Wfb, float* __restrict__ bfv)
{
    const int o = blockIdx.x;        // 0..511
    const int j = threadIdx.x;       // 0..255
    __shared__ float ws[256];
    __shared__ float red[4];

    const float s1 = g1[j] * rsqrtf(v1[j] + 1e-5f);
    const float wo = wout[o * 256 + j];
    ws[j] = wo * s1;
    float bp = wo * (b1[j] - m1[j] * s1);
#pragma unroll
    for (int off = 32; off > 0; off >>= 1) bp += __shfl_down(bp, off);
    if ((j & 63) == 0) red[j >> 6] = bp;
    __syncthreads();

    float acc = 0.f;
#pragma unroll 4
    for (int ic = 0; ic < 256; ++ic)
        acc += ws[ic] * wwg[ic * 256 + j];

    const float s2 = g2[o] * rsqrtf(v2[o] + 1e-5f);
    Wfb[o * 256 + j] = (bf16_t)(acc * s2);
    if (j == 0)
        bfv[o] = s2 * (red[0] + red[1] + red[2] + red[3] + bout[o])
                 - s2 * m2[o] + b2[o];
}

// --------------------------------------------- xA [b,c,n] -> xAt [b,n,c] bf16
__global__ __launch_bounds__(256) void txa_k(
    const float* __restrict__ xA, bf16_t* __restrict__ xAt)
{
    __shared__ float t[32][33];
    const int b = blockIdx.z;
    const int n0 = blockIdx.x * 32, c0 = blockIdx.y * 32;
    const int tx = threadIdx.x, ty = threadIdx.y;
    const float* X = xA + (size_t)b * C_ * N_;
    bf16_t* Y = xAt + (size_t)b * N_ * C_;
#pragma unroll
    for (int r = 0; r < 4; ++r)
        t[ty + r * 8][tx] = X[(size_t)(c0 + ty + r * 8) * N_ + n0 + tx];
    __syncthreads();
#pragma unroll
    for (int r = 0; r < 4; ++r)
        Y[(size_t)(n0 + ty + r * 8) * C_ + c0 + tx] = (bf16_t)t[tx][ty + r * 8];
}

// ------------------------------------------ conv KVQ: W[o,c] * xAt[n,c]^T
__global__ __launch_bounds__(256) void conv_mfma_k(
    const bf16_t* __restrict__ Wb3,
    const float* __restrict__ bk, const float* __restrict__ bv,
    const float* __restrict__ bq, const bf16_t* __restrict__ xAt,
    bf16_t* __restrict__ Kb, bf16_t* __restrict__ Vt, bf16_t* __restrict__ Qt)
{
    __shared__ bf16_t smem[16384];
    const int which = blockIdx.z % 3, b = blockIdx.z / 3;
    const bf16_t* A = Wb3 + which * 131072;
    const float* bias = (which == 0) ? bk : (which == 1 ? bv : bq);
    const bf16_t* Bt = xAt + (size_t)b * N_ * C_;
    const int n0 = blockIdx.x * 128, m0 = blockIdx.y * 128;

    f32x4 acc[4][4];
    ACC_ZERO(acc);
    gemm_bt_128x128(A, C_, Bt, C_, C_, 0, m0, n0, smem, smem + 8192, acc);

    const int lane = threadIdx.x & 63, wave = threadIdx.x >> 6;
    const int q = lane >> 4, l15 = lane & 15;
    const int wr = (wave >> 1) * 64, wc = (wave & 1) * 64;

    if (which == 0) {                     // K: [c, n], n contiguous
        bf16_t* Y = Kb + (size_t)b * IC_ * N_;
#pragma unroll
        for (int i = 0; i < 4; ++i)
#pragma unroll
            for (int r = 0; r < 4; ++r) {
                const int o = m0 + wr + i * 16 + q * 4 + r;
                const float bo = bias[o];
#pragma unroll
                for (int j = 0; j < 4; ++j)
                    Y[(size_t)o * N_ + n0 + wc + j * 16 + l15] =
                        (bf16_t)(acc[i][j][r] + bo);
            }
    } else {                              // V/Q: [n, c], c contiguous
        bf16_t* Y = ((which == 1) ? Vt : Qt) + (size_t)b * N_ * IC_;
#pragma unroll
        for (int i = 0; i < 4; ++i) {
            const int ob = m0 + wr + i * 16 + q * 4;
            float bo[4];
#pragma unroll
            for (int r = 0; r < 4; ++r) bo[r] = bias[ob + r];
#pragma unroll
            for (int j = 0; j < 4; ++j) {
                const int n = n0 + wc + j * 16 + l15;
                bf16x4 v4;
#pragma unroll
                for (int r = 0; r < 4; ++r) v4[r] = (bf16_t)(acc[i][j][r] + bo[r]);
                *(bf16x4*)&Y[(size_t)n * IC_ + ob] = v4;
            }
        }
    }
}

// ---- S^T GEMM (batched): D[m,n]=Qt[m,:].Vt[n,:]; write Pt[b][m,n]=exp bf16,
//      rowsum[b][n] += column sums. LDS stage (stride 136) -> b128 stores.
__global__ __launch_bounds__(256) void s_mfma_t_k(
    const bf16_t* __restrict__ Qt, const bf16_t* __restrict__ Vt,
    bf16_t* __restrict__ Pt, float* __restrict__ rowsum)
{
    __shared__ bf16_t smem[17408];
    const int b  = blockIdx.z;
    const int n0 = blockIdx.x * 128;      // cols (n)
    const int m0 = blockIdx.y * 128;      // rows (m)
    const size_t NIC = (size_t)N_ * IC_;
    const bf16_t* Qb = Qt + (size_t)b * NIC;
    const bf16_t* Vb = Vt + (size_t)b * NIC;
    bf16_t* Pb = Pt + (size_t)b * N_ * N_;
    float* rs = rowsum + b * N_;

    f32x4 acc[4][4];
    ACC_ZERO(acc);
    gemm_bt_128x128(Qb, IC_, Vb, IC_, IC_, 0, m0, n0, smem, smem + 8192, acc);

    const int tid = threadIdx.x;
    const int lane = tid & 63, wave = tid >> 6;
    const int q = lane >> 4, l15 = lane & 15;
    const int wr = (wave >> 1) * 64, wc = (wave & 1) * 64;

#pragma unroll
    for (int j = 0; j < 4; ++j) {
        float cs = 0.f;
#pragma unroll
        for (int i = 0; i < 4; ++i)
#pragma unroll
            for (int r = 0; r < 4; ++r) {
                const float e = __expf(acc[i][j][r]);
                cs += e;
                smem[(wr + i * 16 + q * 4 + r) * 136 + wc + j * 16 + l15] = (bf16_t)e;
            }
        cs += __shfl_xor(cs, 16);
        cs += __shfl_xor(cs, 32);
        if (q == 0) atomicAdd(&rs[n0 + wc + j * 16 + l15], cs);
    }
    __syncthreads();

    const int rr = tid >> 4;              // 0..15
    const int cc = (tid & 15) * 8;        // 0..120
#pragma unroll
    for (int p = 0; p < 8; ++p) {
        const int mm = rr + p * 16;
        const bf16x8 v = *(const bf16x8*)&smem[mm * 136 + cc];
        *(bf16x8*)&Pb[(size_t)(m0 + mm) * N_ + n0 + cc] = v;
    }
}

// --------------- K'[b][c,n] = K[b][c,n] / rowsum[b][n], in-place (batched)
__global__ __launch_bounds__(256) void kscale_k(
    bf16_t* __restrict__ Kb, const float* __restrict__ rowsum)
{
    const size_t i8 = ((size_t)blockIdx.x * 256 + threadIdx.x) * 8;  // 2048 blocks
    const int n = (int)(i8 & (N_ - 1));
    const int b = (int)(i8 >> 20);                 // IC_*N_ = 2^20
    const float* rs = rowsum + b * N_;
    bf16x8 v = *(bf16x8*)&Kb[i8];
    const f32x4 r0 = *(const f32x4*)&rs[n];
    const f32x4 r1 = *(const f32x4*)&rs[n + 4];
#pragma unroll
    for (int k = 0; k < 4; ++k) {
        v[k]     = (bf16_t)((float)v[k]     / r0[k]);
        v[4 + k] = (bf16_t)((float)v[4 + k] / r1[k]);
    }
    *(bf16x8*)&Kb[i8] = v;
}

// ------- av GEMM (batched): avPart[b][z][m][c] = Pt[b][m,kchunk].K'[b][c,kchunk]^T
__global__ __launch_bounds__(256) void av_mfma_k(
    const bf16_t* __restrict__ Pt, const bf16_t* __restrict__ Kb,
    float* __restrict__ avPart)
{
    __shared__ bf16_t smem[16384];
    const int m0 = blockIdx.x * 128;      // rows m
    const int c0 = blockIdx.y * 128;      // cols c
    const int b  = blockIdx.z >> 2;
    const int z  = blockIdx.z & 3;        // splitK=4, 1024-wide chunks
    const size_t NIC = (size_t)N_ * IC_;

    f32x4 acc[4][4];
    ACC_ZERO(acc);
    gemm_bt_128x128(Pt + (size_t)b * N_ * N_, N_, Kb + (size_t)b * NIC, N_,
                    1024, z * 1024, m0, c0, smem, smem + 8192, acc);

    const int lane = threadIdx.x & 63, wave = threadIdx.x >> 6;
    const int q = lane >> 4, l15 = lane & 15;
    const int wr = (wave >> 1) * 64, wc = (wave & 1) * 64;
    float* Y = avPart + (size_t)(b * 4 + z) * NIC;

#pragma unroll
    for (int i = 0; i < 4; ++i)
#pragma unroll
        for (int r = 0; r < 4; ++r) {
            const int m = m0 + wr + i * 16 + q * 4 + r;
#pragma unroll
            for (int j = 0; j < 4; ++j)
                Y[(size_t)m * IC_ + c0 + wc + j * 16 + l15] = acc[i][j][r];
        }
}

// ------------- avTb[b][m][c] = bf16( sum_z avPart[b][z][m][c] )  (batched)
__global__ __launch_bounds__(256) void avred_k(
    const float* __restrict__ avPart, bf16_t* __restrict__ avTb)
{
    const size_t i8 = ((size_t)blockIdx.x * 256 + threadIdx.x) * 8;  // 2048 blocks
    const int b = (int)(i8 >> 20);                       // IC_*N_ = 2^20 elems/batch
    const size_t w = i8 & (((size_t)1 << 20) - 1);
    const float* base = avPart + (size_t)b * 4194304 + w;   // 4 partials x 2^20
    f32x4 s0 = {0.f, 0.f, 0.f, 0.f}, s1 = {0.f, 0.f, 0.f, 0.f};
#pragma unroll
    for (int z = 0; z < 4; ++z) {
        s0 += *(const f32x4*)&base[(size_t)z * 1048576];
        s1 += *(const f32x4*)&base[(size_t)z * 1048576 + 4];
    }
    bf16x8 o;
#pragma unroll
    for (int k = 0; k < 4; ++k) { o[k] = (bf16_t)s0[k]; o[4 + k] = (bf16_t)s1[k]; }
    *(bf16x8*)&avTb[i8] = o;
}

// ------------ final: out = relu( Wf . avT + bfv + xA ), fp32 out (batched)
__global__ __launch_bounds__(256) void out_mfma_k(
    const bf16_t* __restrict__ Wfb, const float* __restrict__ bfv,
    const bf16_t* __restrict__ avTb,
    const float* __restrict__ xA, float* __restrict__ out)
{
    __shared__ bf16_t smem[16384];
    const int b = blockIdx.z;
    const bf16_t* Bt = avTb + (size_t)b * N_ * IC_;
    const int n0 = blockIdx.x * 128, o0 = blockIdx.y * 128;

    f32x4 acc[4][4];
    ACC_ZERO(acc);
    gemm_bt_128x128(Wfb, IC_, Bt, IC_, IC_, 0, o0, n0, smem, smem + 8192, acc);

    const int lane = threadIdx.x & 63, wave = threadIdx.x >> 6;
    const int q = lane >> 4, l15 = lane & 15;
    const int wr = (wave >> 1) * 64, wc = (wave & 1) * 64;

#pragma unroll
    for (int i = 0; i < 4; ++i)
#pragma unroll
        for (int r = 0; r < 4; ++r) {
            const int o = o0 + wr + i * 16 + q * 4 + r;
            const float bo = bfv[o];
#pragma unroll
            for (int j = 0; j < 4; ++j) {
                const int n = n0 + wc + j * 16 + l15;
                const size_t idx = ((size_t)b * C_ + o) * N_ + n;
                out[idx] = fmaxf(acc[i][j][r] + bo + xA[idx], 0.f);
            }
        }
}

// ---------------------------------------------------------------- launcher
extern "C" void kernel_launch(void* const* d_in, const int* in_sizes, int n_in,
                              void* d_out, int out_size, void* d_ws, size_t ws_size,
                              hipStream_t stream)
{
    const float* xA    = (const float*)d_in[0];
    const float* wk    = (const float*)d_in[1];
    const float* bk    = (const float*)d_in[2];
    const float* wv    = (const float*)d_in[3];
    const float* bv    = (const float*)d_in[4];
    const float* wq    = (const float*)d_in[5];
    const float* bq    = (const float*)d_in[6];
    const float* wwg   = (const float*)d_in[7];
    const float* bn1_g = (const float*)d_in[8];
    const float* bn1_b = (const float*)d_in[9];
    const float* bn1_m = (const float*)d_in[10];
    const float* bn1_v = (const float*)d_in[11];
    const float* wout  = (const float*)d_in[12];
    const float* bout  = (const float*)d_in[13];
    const float* bn2_g = (const float*)d_in[14];
    const float* bn2_b = (const float*)d_in[15];
    const float* bn2_m = (const float*)d_in[16];
    const float* bn2_v = (const float*)d_in[17];
    float* out = (float*)d_out;

    // ---- workspace layout (244.4 MB of 256 MiB) ----
    char* p = (char*)d_ws;
    bf16_t* Wb3    = (bf16_t*)p; p += 786432;      // wk|wv|wq bf16
    bf16_t* Wfb    = (bf16_t*)p; p += 262144;      // composed weight [512,256]
    float*  bfv    = (float*)p;  p += 2048;        // composed bias [512]
    bf16_t* xAt    = (bf16_t*)p;                   // [b,n,c] bf16 (dead after conv)
    bf16_t* avTb   = (bf16_t*)p; p += 16777216;    // ALIAS: [b,m,c] bf16 (8.4MB used)
    bf16_t* Kb     = (bf16_t*)p; p += 8388608;     // [b,c,n] (scaled in-place)
    bf16_t* Vt     = (bf16_t*)p; p += 8388608;     // [b,n,c]
    bf16_t* Qt     = (bf16_t*)p; p += 8388608;     // [b,n,c]
    float*  rowsum = (float*)p;  p += 65536;       // [b,n]
    bf16_t* Pt     = (bf16_t*)p; p += 134217728;   // [b,m,n] bf16, all batches
    float*  avPart = (float*)p;  p += 67108864;    // [b,4,m,c] fp32 splitK partials

    castw3_k<<<1536, 256, 0, stream>>>(wk, wv, wq, Wb3);
    wf_k<<<512, 256, 0, stream>>>(wwg, wout, bout, bn1_g, bn1_b, bn1_m, bn1_v,
                                  bn2_g, bn2_b, bn2_m, bn2_v, Wfb, bfv);
    (void)hipMemsetAsync(rowsum, 0, 65536, stream);
    txa_k<<<dim3(N_ / 32, C_ / 32, B_), dim3(32, 8), 0, stream>>>(xA, xAt);
    conv_mfma_k<<<dim3(N_ / 128, IC_ / 128, 3 * B_), 256, 0, stream>>>(
        Wb3, bk, bv, bq, xAt, Kb, Vt, Qt);

    s_mfma_t_k<<<dim3(N_ / 128, N_ / 128, B_), 256, 0, stream>>>(
        Qt, Vt, Pt, rowsum);
    kscale_k<<<2048, 256, 0, stream>>>(Kb, rowsum);
    av_mfma_k<<<dim3(N_ / 128, IC_ / 128, 4 * B_), 256, 0, stream>>>(
        Pt, Kb, avPart);
    avred_k<<<2048, 256, 0, stream>>>(avPart, avTb);

    out_mfma_k<<<dim3(N_ / 128, C_ / 128, B_), 256, 0, stream>>>(
        Wfb, bfv, avTb, xA, out);
}

// Round 6
// 326.780 us; speedup vs baseline: 4.6441x; 1.0616x over previous
//
#include <hip/hip_runtime.h>

// MFB fused non-local block, round 6.
// - XOR-swizzled LDS layout in the shared GEMM core: lane l stages global
//   chunk (l&7)^(srow&7), reads use ((ks*4+q)^(l15&7)) -> ds_read_b128 at
//   the 8-deep floor instead of 16-deep-on-16-banks (kills the 1.3e7
//   SQ_LDS_BANK_CONFLICT inherited from the m97 structure).
// - av splitK 4->2: still 512 blocks (2/CU), avPart traffic halved.

#define N_ 4096
#define C_ 512
#define IC_ 256
#define B_ 4

typedef __bf16 bf16_t;
typedef __bf16 bf16x8 __attribute__((ext_vector_type(8)));
typedef __bf16 bf16x4 __attribute__((ext_vector_type(4)));
typedef float f32x4 __attribute__((ext_vector_type(4)));

#define GLD(g, l) __builtin_amdgcn_global_load_lds(                              \
    (const __attribute__((address_space(1))) void*)(g),                          \
    (__attribute__((address_space(3))) void*)(l), 16, 0, 0)

// ---------------------------------------------------------------------------
// C[128x128] += A[m0.., K] * Bt[n0.., K]^T, bf16 in, fp32 acc. K mult of 64.
// 256 threads = 4 waves; wave (wr,wc) owns 64x64; acc[4][4] of f32x4.
// C/D layout (m89/m91): (i,j,reg) -> row wr+i*16+q*4+reg, col wc+j*16+l15.
// LDS: XOR-swizzled 64-elem rows; slot (row, c) holds global chunk c^(row&7).
// ---------------------------------------------------------------------------
__device__ __forceinline__ void gemm_bt_128x128(
    const bf16_t* __restrict__ A, int lda,
    const bf16_t* __restrict__ Bt, int ldb,
    int K, int kt0, int m0, int n0,
    bf16_t* lsA, bf16_t* lsB, f32x4 acc[4][4])
{
    const int tid  = threadIdx.x;
    const int wave = tid >> 6, lane = tid & 63;
    const int wr = (wave >> 1) * 64, wc = (wave & 1) * 64;
    const int q = lane >> 4, l15 = lane & 15;
    const int srow = lane >> 3;                         // 0..7
    const int scol = (((lane & 7) ^ (srow & 7)) * 8);   // swizzled 8-elem chunk
    const int swz  = l15 & 7;

    for (int kt = kt0; kt < kt0 + K; kt += 64) {
#pragma unroll
        for (int c = 0; c < 4; ++c) {
            const int ch = wave * 4 + c;
            GLD(A  + (size_t)(m0 + ch * 8 + srow) * lda + kt + scol, lsA + ch * 512);
            GLD(Bt + (size_t)(n0 + ch * 8 + srow) * ldb + kt + scol, lsB + ch * 512);
        }
        __syncthreads();
#pragma unroll
        for (int ks = 0; ks < 2; ++ks) {
            bf16x8 af[4], bfr[4];
            const int co = ((ks * 4 + q) ^ swz) * 8;
#pragma unroll
            for (int i = 0; i < 4; ++i) {
                af[i]  = *(const bf16x8*)&lsA[(wr + i * 16 + l15) * 64 + co];
                bfr[i] = *(const bf16x8*)&lsB[(wc + i * 16 + l15) * 64 + co];
            }
#pragma unroll
            for (int i = 0; i < 4; ++i)
#pragma unroll
                for (int j = 0; j < 4; ++j)
                    acc[i][j] = __builtin_amdgcn_mfma_f32_16x16x32_bf16(
                        af[i], bfr[j], acc[i][j], 0, 0, 0);
        }
        __syncthreads();
    }
}

#define ACC_ZERO(acc)                                                           \
    _Pragma("unroll") for (int i = 0; i < 4; ++i)                               \
    _Pragma("unroll") for (int j = 0; j < 4; ++j)                               \
        acc[i][j] = f32x4{0.f, 0.f, 0.f, 0.f};

// --------------------------------------------------- cast wk|wv|wq to bf16
__global__ __launch_bounds__(256) void castw3_k(
    const float* __restrict__ wk, const float* __restrict__ wv,
    const float* __restrict__ wq, bf16_t* __restrict__ Wb3)
{
    const int i = blockIdx.x * 256 + threadIdx.x;   // 393216 total
    float v;
    if      (i < 131072) v = wk[i];
    else if (i < 262144) v = wv[i - 131072];
    else                 v = wq[i - 262144];
    Wb3[i] = (bf16_t)v;
}

// ---- compose Wf = diag(s2) wout diag(s1) wwg, bfv (all biases folded).
__global__ __launch_bounds__(256) void wf_k(
    const float* __restrict__ wwg, const float* __restrict__ wout,
    const float* __restrict__ bout,
    const float* __restrict__ g1, const float* __restrict__ b1,
    const float* __restrict__ m1, const float* __restrict__ v1,
    const float* __restrict__ g2, const float* __restrict__ b2,
    const float* __restrict__ m2, const float* __restrict__ v2,
    bf16_t* __restrict__ Wfb, float* __restrict__ bfv)
{
    const int o = blockIdx.x;        // 0..511
    const int j = threadIdx.x;       // 0..255
    __shared__ float ws[256];
    __shared__ float red[4];

    const float s1 = g1[j] * rsqrtf(v1[j] + 1e-5f);
    const float wo = wout[o * 256 + j];
    ws[j] = wo * s1;
    float bp = wo * (b1[j] - m1[j] * s1);
#pragma unroll
    for (int off = 32; off > 0; off >>= 1) bp += __shfl_down(bp, off);
    if ((j & 63) == 0) red[j >> 6] = bp;
    __syncthreads();

    float acc = 0.f;
#pragma unroll 4
    for (int ic = 0; ic < 256; ++ic)
        acc += ws[ic] * wwg[ic * 256 + j];

    const float s2 = g2[o] * rsqrtf(v2[o] + 1e-5f);
    Wfb[o * 256 + j] = (bf16_t)(acc * s2);
    if (j == 0)
        bfv[o] = s2 * (red[0] + red[1] + red[2] + red[3] + bout[o])
                 - s2 * m2[o] + b2[o];
}

// --------------------------------------------- xA [b,c,n] -> xAt [b,n,c] bf16
__global__ __launch_bounds__(256) void txa_k(
    const float* __restrict__ xA, bf16_t* __restrict__ xAt)
{
    __shared__ float t[32][33];
    const int b = blockIdx.z;
    const int n0 = blockIdx.x * 32, c0 = blockIdx.y * 32;
    const int tx = threadIdx.x, ty = threadIdx.y;
    const float* X = xA + (size_t)b * C_ * N_;
    bf16_t* Y = xAt + (size_t)b * N_ * C_;
#pragma unroll
    for (int r = 0; r < 4; ++r)
        t[ty + r * 8][tx] = X[(size_t)(c0 + ty + r * 8) * N_ + n0 + tx];
    __syncthreads();
#pragma unroll
    for (int r = 0; r < 4; ++r)
        Y[(size_t)(n0 + ty + r * 8) * C_ + c0 + tx] = (bf16_t)t[tx][ty + r * 8];
}

// ------------------------------------------ conv KVQ: W[o,c] * xAt[n,c]^T
__global__ __launch_bounds__(256) void conv_mfma_k(
    const bf16_t* __restrict__ Wb3,
    const float* __restrict__ bk, const float* __restrict__ bv,
    const float* __restrict__ bq, const bf16_t* __restrict__ xAt,
    bf16_t* __restrict__ Kb, bf16_t* __restrict__ Vt, bf16_t* __restrict__ Qt)
{
    __shared__ bf16_t smem[16384];
    const int which = blockIdx.z % 3, b = blockIdx.z / 3;
    const bf16_t* A = Wb3 + which * 131072;
    const float* bias = (which == 0) ? bk : (which == 1 ? bv : bq);
    const bf16_t* Bt = xAt + (size_t)b * N_ * C_;
    const int n0 = blockIdx.x * 128, m0 = blockIdx.y * 128;

    f32x4 acc[4][4];
    ACC_ZERO(acc);
    gemm_bt_128x128(A, C_, Bt, C_, C_, 0, m0, n0, smem, smem + 8192, acc);

    const int lane = threadIdx.x & 63, wave = threadIdx.x >> 6;
    const int q = lane >> 4, l15 = lane & 15;
    const int wr = (wave >> 1) * 64, wc = (wave & 1) * 64;

    if (which == 0) {                     // K: [c, n], n contiguous
        bf16_t* Y = Kb + (size_t)b * IC_ * N_;
#pragma unroll
        for (int i = 0; i < 4; ++i)
#pragma unroll
            for (int r = 0; r < 4; ++r) {
                const int o = m0 + wr + i * 16 + q * 4 + r;
                const float bo = bias[o];
#pragma unroll
                for (int j = 0; j < 4; ++j)
                    Y[(size_t)o * N_ + n0 + wc + j * 16 + l15] =
                        (bf16_t)(acc[i][j][r] + bo);
            }
    } else {                              // V/Q: [n, c], c contiguous
        bf16_t* Y = ((which == 1) ? Vt : Qt) + (size_t)b * N_ * IC_;
#pragma unroll
        for (int i = 0; i < 4; ++i) {
            const int ob = m0 + wr + i * 16 + q * 4;
            float bo[4];
#pragma unroll
            for (int r = 0; r < 4; ++r) bo[r] = bias[ob + r];
#pragma unroll
            for (int j = 0; j < 4; ++j) {
                const int n = n0 + wc + j * 16 + l15;
                bf16x4 v4;
#pragma unroll
                for (int r = 0; r < 4; ++r) v4[r] = (bf16_t)(acc[i][j][r] + bo[r]);
                *(bf16x4*)&Y[(size_t)n * IC_ + ob] = v4;
            }
        }
    }
}

// ---- S^T GEMM (batched): D[m,n]=Qt[m,:].Vt[n,:]; write Pt[b][m,n]=exp bf16,
//      rowsum[b][n] += column sums. LDS stage (stride 136) -> b128 stores.
__global__ __launch_bounds__(256) void s_mfma_t_k(
    const bf16_t* __restrict__ Qt, const bf16_t* __restrict__ Vt,
    bf16_t* __restrict__ Pt, float* __restrict__ rowsum)
{
    __shared__ bf16_t smem[17408];
    const int b  = blockIdx.z;
    const int n0 = blockIdx.x * 128;      // cols (n)
    const int m0 = blockIdx.y * 128;      // rows (m)
    const size_t NIC = (size_t)N_ * IC_;
    const bf16_t* Qb = Qt + (size_t)b * NIC;
    const bf16_t* Vb = Vt + (size_t)b * NIC;
    bf16_t* Pb = Pt + (size_t)b * N_ * N_;
    float* rs = rowsum + b * N_;

    f32x4 acc[4][4];
    ACC_ZERO(acc);
    gemm_bt_128x128(Qb, IC_, Vb, IC_, IC_, 0, m0, n0, smem, smem + 8192, acc);

    const int tid = threadIdx.x;
    const int lane = tid & 63, wave = tid >> 6;
    const int q = lane >> 4, l15 = lane & 15;
    const int wr = (wave >> 1) * 64, wc = (wave & 1) * 64;

#pragma unroll
    for (int j = 0; j < 4; ++j) {
        float cs = 0.f;
#pragma unroll
        for (int i = 0; i < 4; ++i)
#pragma unroll
            for (int r = 0; r < 4; ++r) {
                const float e = __expf(acc[i][j][r]);
                cs += e;
                smem[(wr + i * 16 + q * 4 + r) * 136 + wc + j * 16 + l15] = (bf16_t)e;
            }
        cs += __shfl_xor(cs, 16);
        cs += __shfl_xor(cs, 32);
        if (q == 0) atomicAdd(&rs[n0 + wc + j * 16 + l15], cs);
    }
    __syncthreads();

    const int rr = tid >> 4;              // 0..15
    const int cc = (tid & 15) * 8;        // 0..120
#pragma unroll
    for (int p = 0; p < 8; ++p) {
        const int mm = rr + p * 16;
        const bf16x8 v = *(const bf16x8*)&smem[mm * 136 + cc];
        *(bf16x8*)&Pb[(size_t)(m0 + mm) * N_ + n0 + cc] = v;
    }
}

// --------------- K'[b][c,n] = K[b][c,n] / rowsum[b][n], in-place (batched)
__global__ __launch_bounds__(256) void kscale_k(
    bf16_t* __restrict__ Kb, const float* __restrict__ rowsum)
{
    const size_t i8 = ((size_t)blockIdx.x * 256 + threadIdx.x) * 8;  // 2048 blocks
    const int n = (int)(i8 & (N_ - 1));
    const int b = (int)(i8 >> 20);                 // IC_*N_ = 2^20
    const float* rs = rowsum + b * N_;
    bf16x8 v = *(bf16x8*)&Kb[i8];
    const f32x4 r0 = *(const f32x4*)&rs[n];
    const f32x4 r1 = *(const f32x4*)&rs[n + 4];
#pragma unroll
    for (int k = 0; k < 4; ++k) {
        v[k]     = (bf16_t)((float)v[k]     / r0[k]);
        v[4 + k] = (bf16_t)((float)v[4 + k] / r1[k]);
    }
    *(bf16x8*)&Kb[i8] = v;
}

// ------- av GEMM (batched): avPart[z][b][m][c] = Pt[b][m,kchunk].K'[b][c,kchunk]^T
__global__ __launch_bounds__(256) void av_mfma_k(
    const bf16_t* __restrict__ Pt, const bf16_t* __restrict__ Kb,
    float* __restrict__ avPart)
{
    __shared__ bf16_t smem[16384];
    const int m0 = blockIdx.x * 128;      // rows m
    const int c0 = blockIdx.y * 128;      // cols c
    const int b  = blockIdx.z >> 1;
    const int z  = blockIdx.z & 1;        // splitK=2, 2048-wide chunks
    const size_t NIC = (size_t)N_ * IC_;

    f32x4 acc[4][4];
    ACC_ZERO(acc);
    gemm_bt_128x128(Pt + (size_t)b * N_ * N_, N_, Kb + (size_t)b * NIC, N_,
                    2048, z * 2048, m0, c0, smem, smem + 8192, acc);

    const int lane = threadIdx.x & 63, wave = threadIdx.x >> 6;
    const int q = lane >> 4, l15 = lane & 15;
    const int wr = (wave >> 1) * 64, wc = (wave & 1) * 64;
    float* Y = avPart + ((size_t)z * B_ + b) * NIC;

#pragma unroll
    for (int i = 0; i < 4; ++i)
#pragma unroll
        for (int r = 0; r < 4; ++r) {
            const int m = m0 + wr + i * 16 + q * 4 + r;
#pragma unroll
            for (int j = 0; j < 4; ++j)
                Y[(size_t)m * IC_ + c0 + wc + j * 16 + l15] = acc[i][j][r];
        }
}

// ------------- avTb[b][m][c] = bf16( sum_z avPart[z][b][m][c] )  (batched)
__global__ __launch_bounds__(256) void avred_k(
    const float* __restrict__ avPart, bf16_t* __restrict__ avTb)
{
    const size_t i8 = ((size_t)blockIdx.x * 256 + threadIdx.x) * 8;  // 2048 blocks
    const float* base = avPart + i8;          // [b][m][c] flat, z stride 4*2^20
    f32x4 s0 = *(const f32x4*)&base[0];
    f32x4 s1 = *(const f32x4*)&base[4];
    s0 += *(const f32x4*)&base[4194304];
    s1 += *(const f32x4*)&base[4194304 + 4];
    bf16x8 o;
#pragma unroll
    for (int k = 0; k < 4; ++k) { o[k] = (bf16_t)s0[k]; o[4 + k] = (bf16_t)s1[k]; }
    *(bf16x8*)&avTb[i8] = o;
}

// ------------ final: out = relu( Wf . avT + bfv + xA ), fp32 out (batched)
__global__ __launch_bounds__(256) void out_mfma_k(
    const bf16_t* __restrict__ Wfb, const float* __restrict__ bfv,
    const bf16_t* __restrict__ avTb,
    const float* __restrict__ xA, float* __restrict__ out)
{
    __shared__ bf16_t smem[16384];
    const int b = blockIdx.z;
    const bf16_t* Bt = avTb + (size_t)b * N_ * IC_;
    const int n0 = blockIdx.x * 128, o0 = blockIdx.y * 128;

    f32x4 acc[4][4];
    ACC_ZERO(acc);
    gemm_bt_128x128(Wfb, IC_, Bt, IC_, IC_, 0, o0, n0, smem, smem + 8192, acc);

    const int lane = threadIdx.x & 63, wave = threadIdx.x >> 6;
    const int q = lane >> 4, l15 = lane & 15;
    const int wr = (wave >> 1) * 64, wc = (wave & 1) * 64;

#pragma unroll
    for (int i = 0; i < 4; ++i)
#pragma unroll
        for (int r = 0; r < 4; ++r) {
            const int o = o0 + wr + i * 16 + q * 4 + r;
            const float bo = bfv[o];
#pragma unroll
            for (int j = 0; j < 4; ++j) {
                const int n = n0 + wc + j * 16 + l15;
                const size_t idx = ((size_t)b * C_ + o) * N_ + n;
                out[idx] = fmaxf(acc[i][j][r] + bo + xA[idx], 0.f);
            }
        }
}

// ---------------------------------------------------------------- launcher
extern "C" void kernel_launch(void* const* d_in, const int* in_sizes, int n_in,
                              void* d_out, int out_size, void* d_ws, size_t ws_size,
                              hipStream_t stream)
{
    const float* xA    = (const float*)d_in[0];
    const float* wk    = (const float*)d_in[1];
    const float* bk    = (const float*)d_in[2];
    const float* wv    = (const float*)d_in[3];
    const float* bv    = (const float*)d_in[4];
    const float* wq    = (const float*)d_in[5];
    const float* bq    = (const float*)d_in[6];
    const float* wwg   = (const float*)d_in[7];
    const float* bn1_g = (const float*)d_in[8];
    const float* bn1_b = (const float*)d_in[9];
    const float* bn1_m = (const float*)d_in[10];
    const float* bn1_v = (const float*)d_in[11];
    const float* wout  = (const float*)d_in[12];
    const float* bout  = (const float*)d_in[13];
    const float* bn2_g = (const float*)d_in[14];
    const float* bn2_b = (const float*)d_in[15];
    const float* bn2_m = (const float*)d_in[16];
    const float* bn2_v = (const float*)d_in[17];
    float* out = (float*)d_out;

    // ---- workspace layout (211 MB of 256 MiB) ----
    char* p = (char*)d_ws;
    bf16_t* Wb3    = (bf16_t*)p; p += 786432;      // wk|wv|wq bf16
    bf16_t* Wfb    = (bf16_t*)p; p += 262144;      // composed weight [512,256]
    float*  bfv    = (float*)p;  p += 2048;        // composed bias [512]
    bf16_t* xAt    = (bf16_t*)p;                   // [b,n,c] bf16 (dead after conv)
    bf16_t* avTb   = (bf16_t*)p; p += 16777216;    // ALIAS: [b,m,c] bf16 (8.4MB used)
    bf16_t* Kb     = (bf16_t*)p; p += 8388608;     // [b,c,n] (scaled in-place)
    bf16_t* Vt     = (bf16_t*)p; p += 8388608;     // [b,n,c]
    bf16_t* Qt     = (bf16_t*)p; p += 8388608;     // [b,n,c]
    float*  rowsum = (float*)p;  p += 65536;       // [b,n]
    bf16_t* Pt     = (bf16_t*)p; p += 134217728;   // [b,m,n] bf16, all batches
    float*  avPart = (float*)p;  p += 33554432;    // [2][b,m,c] fp32 splitK partials

    castw3_k<<<1536, 256, 0, stream>>>(wk, wv, wq, Wb3);
    wf_k<<<512, 256, 0, stream>>>(wwg, wout, bout, bn1_g, bn1_b, bn1_m, bn1_v,
                                  bn2_g, bn2_b, bn2_m, bn2_v, Wfb, bfv);
    (void)hipMemsetAsync(rowsum, 0, 65536, stream);
    txa_k<<<dim3(N_ / 32, C_ / 32, B_), dim3(32, 8), 0, stream>>>(xA, xAt);
    conv_mfma_k<<<dim3(N_ / 128, IC_ / 128, 3 * B_), 256, 0, stream>>>(
        Wb3, bk, bv, bq, xAt, Kb, Vt, Qt);

    s_mfma_t_k<<<dim3(N_ / 128, N_ / 128, B_), 256, 0, stream>>>(
        Qt, Vt, Pt, rowsum);
    kscale_k<<<2048, 256, 0, stream>>>(Kb, rowsum);
    av_mfma_k<<<dim3(N_ / 128, IC_ / 128, 2 * B_), 256, 0, stream>>>(
        Pt, Kb, avPart);
    avred_k<<<2048, 256, 0, stream>>>(avPart, avTb);

    out_mfma_k<<<dim3(N_ / 128, C_ / 128, B_), 256, 0, stream>>>(
        Wfb, bfv, avTb, xA, out);
}